// Round 5
// baseline (143.406 us; speedup 1.0000x reference)
//
#include <hip/hip_runtime.h>
#include <hip/hip_fp16.h>
#include <cstdint>
#include <cstddef>

#define N_Q 4096
#define M_K 16384
#define LNB 96
#define CH  512
#define NH  8

typedef _Float16 half8  __attribute__((ext_vector_type(8)));
typedef _Float16 h2     __attribute__((ext_vector_type(2)));
typedef float    floatx4 __attribute__((ext_vector_type(4)));
typedef float    floatx2 __attribute__((ext_vector_type(2)));

union H8 { half8 v; h2 p[4]; };

__device__ __forceinline__ h2 cvt2(float a, float b) {
    return __builtin_bit_cast(h2, __builtin_amdgcn_cvt_pkrtz(a, b));
}

__device__ __forceinline__ void async16(const void* g, void* l) {
    __builtin_amdgcn_global_load_lds(
        (const __attribute__((address_space(1))) void*)g,
        (__attribute__((address_space(3))) void*)l, 16, 0, 0);
}

// DPP butterfly add over an 8-lane octet (pure VALU).
template<int CTRL>
__device__ __forceinline__ float dpp_addf(float x) {
    int xi = __builtin_bit_cast(int, x);
    int yi = __builtin_amdgcn_update_dpp(xi, xi, CTRL, 0xF, 0xF, false);
    return x + __builtin_bit_cast(float, yi);
}
__device__ __forceinline__ float octet_sum(float x) {
    x = dpp_addf<0x141>(x);   // row_half_mirror
    x = dpp_addf<0x4E>(x);    // quad xor2
    x = dpp_addf<0xB1>(x);    // quad xor1
    return x;
}

// ---------------- fused weight convert: wIn (786432 f) ++ wOut (262144 f) -> fp16
__global__ void cvt_weights(const float* __restrict__ wIn, const float* __restrict__ wOut,
                            _Float16* __restrict__ dst) {
    const size_t i = (size_t)blockIdx.x * blockDim.x + threadIdx.x;   // float4 index
    const float4 v = (i < 196608) ? ((const float4*)wIn)[i]
                                  : ((const float4*)wOut)[i - 196608];
    h2 a = cvt2(v.x, v.y);
    h2 b = cvt2(v.z, v.w);
    *(h2*)&dst[i * 4]     = a;
    *(h2*)&dst[i * 4 + 2] = b;
}

// ---------------- small GEMM body (TM x 128, BK=32), used for Q and out proj ----
template<int OUTF16, int TM, int AFP32>
__device__ __forceinline__ void gemm_body(
    const void* __restrict__ Ap, const _Float16* __restrict__ Bw,
    const float* __restrict__ bias, void* __restrict__ outp, float oscale,
    int bm, int bn)
{
    constexpr int MI = TM / 32;
    __shared__ alignas(16) _Float16 As[TM * 32];
    __shared__ alignas(16) _Float16 Bs[128 * 32];

    const int t    = threadIdx.x;
    const int lane = t & 63;
    const int wave = t >> 6;
    const int wm   = wave >> 1, wn = wave & 1;

    floatx4 acc[MI][4] = {};

    const int rowL = t >> 2;
    const int kcol = (t & 3) * 8;
    const _Float16* gB = Bw + (size_t)(bn * 128 + rowL) * CH + kcol;
    _Float16* lB = &Bs[rowL * 32 + kcol];

    const _Float16* gA16 = nullptr; _Float16* lA16 = nullptr;
    const float* gA32 = nullptr; _Float16* lA32 = nullptr;
    if constexpr (AFP32) {
        gA32 = (const float*)Ap + (size_t)(bm * TM + rowL) * CH + kcol;
        lA32 = &As[rowL * 32 + kcol];
    } else {
        gA16 = (const _Float16*)Ap + (size_t)(bm * TM + rowL) * CH + kcol;
        lA16 = &As[rowL * 32 + kcol];
    }

    const int r0 = lane & 15;
    const int ko = (lane >> 4) * 8;

    for (int kt = 0; kt < CH / 32; ++kt) {
        if constexpr (AFP32) {
            const float* ga = gA32 + kt * 32;
            float4 x0 = ((const float4*)ga)[0], x1 = ((const float4*)ga)[1];
            H8 o0;
            o0.p[0] = cvt2(x0.x, x0.y);
            o0.p[1] = cvt2(x0.z, x0.w);
            o0.p[2] = cvt2(x1.x, x1.y);
            o0.p[3] = cvt2(x1.z, x1.w);
            *(half8*)lA32 = o0.v;
        } else {
            const _Float16* a0 = gA16 + kt * 32;
            async16(a0, lA16);
        }
        const _Float16* b0 = gB + kt * 32;
        async16(b0,           lB);
        async16(b0 + 64 * CH, lB + 64 * 32);
        __syncthreads();

        half8 af[MI], bf[4];
        #pragma unroll
        for (int mi = 0; mi < MI; ++mi)
            af[mi] = *(const half8*)&As[(wm * (TM / 2) + mi * 16 + r0) * 32 + ko];
        #pragma unroll
        for (int ni = 0; ni < 4; ++ni)
            bf[ni] = *(const half8*)&Bs[(wn * 64 + ni * 16 + r0) * 32 + ko];
        #pragma unroll
        for (int mi = 0; mi < MI; ++mi)
            #pragma unroll
            for (int ni = 0; ni < 4; ++ni)
                acc[mi][ni] = __builtin_amdgcn_mfma_f32_16x16x32_f16(
                    af[mi], bf[ni], acc[mi][ni], 0, 0, 0);
        __syncthreads();
    }

    #pragma unroll
    for (int mi = 0; mi < MI; ++mi) {
        #pragma unroll
        for (int ni = 0; ni < 4; ++ni) {
            const int col = bn * 128 + wn * 64 + ni * 16 + (lane & 15);
            const float bv = bias[col];
            #pragma unroll
            for (int r = 0; r < 4; ++r) {
                const int row = bm * TM + wm * (TM / 2) + mi * 16 + (lane >> 4) * 4 + r;
                const float v = (acc[mi][ni][r] + bv) * oscale;
                if (OUTF16) ((_Float16*)outp)[(size_t)row * CH + col] = (_Float16)v;
                else        ((float*)outp)[(size_t)row * CH + col]    = v;
            }
        }
    }
}

template<int OUTF16, int TM, int AFP32>
__global__ __launch_bounds__(256) void gemm_k(
    const void* __restrict__ A, const _Float16* __restrict__ Bw,
    const float* __restrict__ bias, void* __restrict__ outp, float oscale)
{
    gemm_body<OUTF16, TM, AFP32>(A, Bw, bias, outp, oscale, blockIdx.x, blockIdx.y);
}

// ---------------- pipelined K/V projection GEMM ----------------
// 128x128 tile, BK=64, fp32 A converted in-register, XOR-swizzled LDS,
// next-step global loads issued before the MFMA phase (latency hidden).
__global__ __launch_bounds__(256) void gemm_kv(
    const float* __restrict__ keyp, const float* __restrict__ valp,
    const _Float16* __restrict__ w16, const float* __restrict__ bIn,
    _Float16* __restrict__ k16, _Float16* __restrict__ v16)
{
    const int z = blockIdx.z;
    const float*    Ap   = z ? valp : keyp;
    const _Float16* Bw   = w16 + (size_t)(z ? 1024 : 512) * 512;
    const float*    bias = bIn + (z ? 1024 : 512);
    _Float16*       outp = z ? v16 : k16;
    const int bm = blockIdx.x, bn = blockIdx.y;

    __shared__ alignas(16) _Float16 As[128 * 64];   // 16KB, rows of 8 granules (16B)
    __shared__ alignas(16) _Float16 Bs[128 * 64];   // 16KB

    const int t    = threadIdx.x;
    const int lane = t & 63;
    const int wave = t >> 6;
    const int wm   = wave >> 1, wn = wave & 1;

    // staging: thread t owns row r2 = t>>1, column half hf (32 cols each)
    const int r2   = t >> 1;
    const int hf   = t & 1;
    const int swzr = r2 & 7;
    const float*    gA = Ap + (size_t)(bm * 128 + r2) * CH + hf * 32;
    const _Float16* gB = Bw + (size_t)(bn * 128 + r2) * CH + hf * 32;
    _Float16* wA = &As[r2 * 64];
    _Float16* wB = &Bs[r2 * 64];

    floatx4 acc[4][4] = {};
    float4 ab[8]; int4 bb[4];

    // prologue: loads for kt=0
    #pragma unroll
    for (int i = 0; i < 8; ++i) ab[i] = ((const float4*)gA)[i];
    #pragma unroll
    for (int i = 0; i < 4; ++i) bb[i] = ((const int4*)gB)[i];

    const int r0 = lane & 15, hi = lane >> 4;
    const int rsw = r0 & 7;

    for (int kt = 0; kt < 8; ++kt) {
        // consume staged regs -> LDS (granule-swizzled)
        #pragma unroll
        for (int i2 = 0; i2 < 4; ++i2) {
            H8 o;
            o.p[0] = cvt2(ab[2*i2].x,   ab[2*i2].y);
            o.p[1] = cvt2(ab[2*i2].z,   ab[2*i2].w);
            o.p[2] = cvt2(ab[2*i2+1].x, ab[2*i2+1].y);
            o.p[3] = cvt2(ab[2*i2+1].z, ab[2*i2+1].w);
            const int g = hf * 4 + i2;
            *(half8*)&wA[(g ^ swzr) * 8] = o.v;
        }
        #pragma unroll
        for (int i = 0; i < 4; ++i) {
            const int g = hf * 4 + i;
            *(int4*)&wB[(g ^ swzr) * 8] = bb[i];
        }
        __syncthreads();

        // issue next K-step's loads — they complete under the MFMA phase
        if (kt < 7) {
            const float*    ga = gA + (kt + 1) * 64;
            const _Float16* gb = gB + (kt + 1) * 64;
            #pragma unroll
            for (int i = 0; i < 8; ++i) ab[i] = ((const float4*)ga)[i];
            #pragma unroll
            for (int i = 0; i < 4; ++i) bb[i] = ((const int4*)gb)[i];
        }

        // compute: two k32 halves, 16 MFMA each
        #pragma unroll
        for (int kh = 0; kh < 2; ++kh) {
            half8 af[4], bf[4];
            const int gg = kh * 4 + hi;
            #pragma unroll
            for (int mi = 0; mi < 4; ++mi)
                af[mi] = *(const half8*)&As[(wm * 64 + mi * 16 + r0) * 64 + ((gg ^ rsw) * 8)];
            #pragma unroll
            for (int ni = 0; ni < 4; ++ni)
                bf[ni] = *(const half8*)&Bs[(wn * 64 + ni * 16 + r0) * 64 + ((gg ^ rsw) * 8)];
            #pragma unroll
            for (int mi = 0; mi < 4; ++mi)
                #pragma unroll
                for (int ni = 0; ni < 4; ++ni)
                    acc[mi][ni] = __builtin_amdgcn_mfma_f32_16x16x32_f16(
                        af[mi], bf[ni], acc[mi][ni], 0, 0, 0);
        }
        __syncthreads();
    }

    // epilogue
    #pragma unroll
    for (int mi = 0; mi < 4; ++mi) {
        #pragma unroll
        for (int ni = 0; ni < 4; ++ni) {
            const int col = bn * 128 + wn * 64 + ni * 16 + (lane & 15);
            const float bv = bias[col];
            #pragma unroll
            for (int r = 0; r < 4; ++r) {
                const int row = bm * 128 + wm * 64 + mi * 16 + (lane >> 4) * 4 + r;
                outp[(size_t)row * CH + col] = (_Float16)(acc[mi][ni][r] + bv);
            }
        }
    }
}

// ---------------- local attention: one block (256 thr) per query ----------------
__global__ __launch_bounds__(256) void attn_kernel(
    const _Float16* __restrict__ q16, const _Float16* __restrict__ k16,
    const _Float16* __restrict__ v16, const int* __restrict__ ipair,
    const int* __restrict__ ibatch, const int* __restrict__ kcnt,
    _Float16* __restrict__ op16, float* __restrict__ aout)
{
    __shared__ uint32_t vmask[LNB];       // row byte-offset | (masked<<31)
    __shared__ float    pls[LNB * 9];     // logits -> probs (stride 9)
    __shared__ __half2  pph[LNB * 9];     // probs pre-packed {p,p} fp16
    __shared__ float    part[4][CH];      // per-wave PV partials

    const int t = threadIdx.x;
    // XCD swizzle: batch b = n/512 -> XCD b (one batch's K+V fp16 fits one L2)
    const int n = ((blockIdx.x & 7) << 9) | (blockIdx.x >> 3);

    if (t < LNB) {
        const int idx = ipair[(size_t)n * LNB + t];
        const int b   = ibatch[n];
        int off = 0;
        for (int i = 0; i < b; ++i) off += kcnt[i];
        const uint32_t vo = (uint32_t)((idx < 0 ? 0 : (idx + off)) * (CH * 2));
        vmask[t] = vo | (idx < 0 ? 0x80000000u : 0u);
    }
    __syncthreads();

    const int lane = t & 63, wv = t >> 6;
    const int h    = lane >> 3;           // head for this lane
    const int l0   = wv * 24;             // wave's contiguous l-chunk

    // ---- phase 1: logits. lane owns dims [lane*8, +8); octet = one head.
    {
        const half8 qv = *(const half8*)(q16 + (size_t)n * CH + lane * 8);
        H8 qu; qu.v = qv;
        const char* kbase = (const char*)k16 + lane * 16;
        const int4* vb = (const int4*)&vmask[l0];
        for (int g = 0; g < 3; ++g) {
            const int4 w0 = vb[2 * g], w1 = vb[2 * g + 1];
            uint32_t vm8[8] = {(uint32_t)w0.x, (uint32_t)w0.y, (uint32_t)w0.z, (uint32_t)w0.w,
                               (uint32_t)w1.x, (uint32_t)w1.y, (uint32_t)w1.z, (uint32_t)w1.w};
            #pragma unroll
            for (int j = 0; j < 8; ++j) {
                const uint32_t vms = __builtin_amdgcn_readfirstlane(vm8[j]);
                H8 ku; ku.v = *(const half8*)(kbase + (vms & 0x7fffffffu));
                float acc = 0.f;
                #pragma unroll
                for (int u = 0; u < 4; ++u)
                    acc = __builtin_amdgcn_fdot2(qu.p[u], ku.p[u], acc, false);
                acc = octet_sum(acc);
                if ((lane & 7) == 0)
                    pls[(l0 + g * 8 + j) * 9 + h] = (vms & 0x80000000u) ? -1e30f : acc;
            }
        }
    }
    __syncthreads();

    // ---- phase 2: softmax over L per head (hh = t>>5, j = t&31)
    {
        const int hh = t >> 5, j = t & 31;
        const float v0 = pls[j * 9 + hh];
        const float v1 = pls[(j + 32) * 9 + hh];
        const float v2 = pls[(j + 64) * 9 + hh];
        float m = fmaxf(v0, fmaxf(v1, v2));
        #pragma unroll
        for (int s = 16; s >= 1; s >>= 1) m = fmaxf(m, __shfl_xor(m, s, 32));
        const float e0 = __expf(v0 - m), e1 = __expf(v1 - m), e2 = __expf(v2 - m);
        float ssum = e0 + e1 + e2;
        #pragma unroll
        for (int s = 16; s >= 1; s >>= 1) ssum += __shfl_xor(ssum, s, 32);
        const float rinv = 1.0f / ssum;
        const float p0 = e0 * rinv, p1 = e1 * rinv, p2 = e2 * rinv;
        pls[j * 9 + hh]        = p0;
        pls[(j + 32) * 9 + hh] = p1;
        pls[(j + 64) * 9 + hh] = p2;
        pph[j * 9 + hh]        = __half2half2(__float2half_rn(p0));
        pph[(j + 32) * 9 + hh] = __half2half2(__float2half_rn(p1));
        pph[(j + 64) * 9 + hh] = __half2half2(__float2half_rn(p2));
    }
    __syncthreads();

    // ---- attn_mean (output 1)
    if (t < LNB) {
        float s = 0.f;
        #pragma unroll
        for (int u = 0; u < NH; ++u) s += pls[t * 9 + u];
        aout[(size_t)n * LNB + t] = s * (1.0f / NH);
    }

    // ---- phase 3: PV. wave owns l in [l0, l0+24), lane owns 8 dims.
    {
        float accf[8] = {};
        const char* vbase = (const char*)v16 + lane * 16;
        const int4* vb = (const int4*)&vmask[l0];
        const __half2 hz = __half2half2(__float2half_rn(0.f));
        for (int g = 0; g < 3; ++g) {
            const int4 w0 = vb[2 * g], w1 = vb[2 * g + 1];
            uint32_t vm8[8] = {(uint32_t)w0.x, (uint32_t)w0.y, (uint32_t)w0.z, (uint32_t)w0.w,
                               (uint32_t)w1.x, (uint32_t)w1.y, (uint32_t)w1.z, (uint32_t)w1.w};
            __half2 a0 = hz, a1 = hz, a2 = hz, a3 = hz;
            #pragma unroll
            for (int j = 0; j < 8; ++j) {
                const uint32_t vms = __builtin_amdgcn_readfirstlane(vm8[j]);
                const half8 vv = *(const half8*)(vbase + (vms & 0x7fffffffu));
                union { half8 v; __half2 q[4]; } vu; vu.v = vv;
                const __half2 pp = pph[(l0 + g * 8 + j) * 9 + h];
                a0 = __hfma2(pp, vu.q[0], a0);
                a1 = __hfma2(pp, vu.q[1], a1);
                a2 = __hfma2(pp, vu.q[2], a2);
                a3 = __hfma2(pp, vu.q[3], a3);
            }
            float2 f;
            f = __half22float2(a0); accf[0] += f.x; accf[1] += f.y;
            f = __half22float2(a1); accf[2] += f.x; accf[3] += f.y;
            f = __half22float2(a2); accf[4] += f.x; accf[5] += f.y;
            f = __half22float2(a3); accf[6] += f.x; accf[7] += f.y;
        }
        floatx4 lo, hi;
        #pragma unroll
        for (int u = 0; u < 4; ++u) { lo[u] = accf[u]; hi[u] = accf[u + 4]; }
        *(floatx4*)&part[wv][lane * 8]     = lo;
        *(floatx4*)&part[wv][lane * 8 + 4] = hi;
    }
    __syncthreads();

    // ---- final cross-wave reduce: thread t owns dims 2t, 2t+1
    {
        const int c = t * 2;
        floatx2 s = *(const floatx2*)&part[0][c];
        #pragma unroll
        for (int w = 1; w < 4; ++w) {
            floatx2 pw = *(const floatx2*)&part[w][c];
            s[0] += pw[0]; s[1] += pw[1];
        }
        h2 o; o[0] = (_Float16)s[0]; o[1] = (_Float16)s[1];
        *(h2*)&op16[(size_t)n * CH + c] = o;
    }
}

extern "C" void kernel_launch(void* const* d_in, const int* in_sizes, int n_in,
                              void* d_out, int out_size, void* d_ws, size_t ws_size,
                              hipStream_t stream)
{
    const float* query = (const float*)d_in[0];
    const float* key   = (const float*)d_in[1];
    const float* value = (const float*)d_in[2];
    const int*   ipair = (const int*)d_in[3];
    const int*   kcnt  = (const int*)d_in[5];
    const int*   ibat  = (const int*)d_in[6];
    const float* wIn   = (const float*)d_in[7];
    const float* bIn   = (const float*)d_in[8];
    const float* wOut  = (const float*)d_in[9];
    const float* bOut  = (const float*)d_in[10];

    float* out  = (float*)d_out;
    float* aout = out + (size_t)N_Q * CH;

    char* ws = (char*)d_ws;
    _Float16* w16  = (_Float16*)(ws);                // in-proj weights fp16 (1.5MB)
    _Float16* wo16 = (_Float16*)(ws + 1572864);      // out-proj weights fp16 (contiguous)
    _Float16* q16  = (_Float16*)(ws + 2097152);      // 4MB
    _Float16* k16  = (_Float16*)(ws + 6291456);      // 16MB
    _Float16* v16  = (_Float16*)(ws + 23068672);     // 16MB
    _Float16* op16 = (_Float16*)(ws + 39845888);     // 4MB

    // one fused weight convert (wIn ++ wOut -> w16 ++ wo16)
    cvt_weights<<<1024, 256, 0, stream>>>(wIn, wOut, w16);

    // Q projection with fused fp32->fp16 A staging (scaling folded in)
    gemm_k<1, 64, 1><<<dim3(64, 4), 256, 0, stream>>>(query, w16, bIn, q16, 0.125f);

    // pipelined K/V projections (fused fp32->fp16, swizzled LDS, prefetch)
    gemm_kv<<<dim3(128, 4, 2), 256, 0, stream>>>(key, value, w16, bIn, k16, v16);

    attn_kernel<<<4096, 256, 0, stream>>>(q16, k16, v16, ipair, ibat, kcnt, op16, aout);

    gemm_k<0, 64, 0><<<dim3(64, 4), 256, 0, stream>>>(op16, wo16, bOut, d_out, 1.0f);
}

// Round 6
// 114.060 us; speedup vs baseline: 1.2573x; 1.2573x over previous
//
#include <hip/hip_runtime.h>
#include <hip/hip_fp16.h>
#include <cstdint>
#include <cstddef>

#define N_Q 4096
#define M_K 16384
#define LNB 96
#define CH  512
#define NH  8

typedef _Float16 half8  __attribute__((ext_vector_type(8)));
typedef _Float16 h2     __attribute__((ext_vector_type(2)));
typedef float    floatx4 __attribute__((ext_vector_type(4)));
typedef float    floatx2 __attribute__((ext_vector_type(2)));

union H8 { half8 v; h2 p[4]; };

__device__ __forceinline__ h2 cvt2(float a, float b) {
    return __builtin_bit_cast(h2, __builtin_amdgcn_cvt_pkrtz(a, b));
}

__device__ __forceinline__ void async16(const void* g, void* l) {
    __builtin_amdgcn_global_load_lds(
        (const __attribute__((address_space(1))) void*)g,
        (__attribute__((address_space(3))) void*)l, 16, 0, 0);
}

// DPP butterfly add over an 8-lane octet (pure VALU).
template<int CTRL>
__device__ __forceinline__ float dpp_addf(float x) {
    int xi = __builtin_bit_cast(int, x);
    int yi = __builtin_amdgcn_update_dpp(xi, xi, CTRL, 0xF, 0xF, false);
    return x + __builtin_bit_cast(float, yi);
}
__device__ __forceinline__ float octet_sum(float x) {
    x = dpp_addf<0x141>(x);   // row_half_mirror
    x = dpp_addf<0x4E>(x);    // quad xor2
    x = dpp_addf<0xB1>(x);    // quad xor1
    return x;
}

// ---------------- fused weight convert: wIn (786432 f) ++ wOut (262144 f) -> fp16
__global__ void cvt_weights(const float* __restrict__ wIn, const float* __restrict__ wOut,
                            _Float16* __restrict__ dst) {
    const size_t i = (size_t)blockIdx.x * blockDim.x + threadIdx.x;   // float4 index
    const float4 v = (i < 196608) ? ((const float4*)wIn)[i]
                                  : ((const float4*)wOut)[i - 196608];
    h2 a = cvt2(v.x, v.y);
    h2 b = cvt2(v.z, v.w);
    *(h2*)&dst[i * 4]     = a;
    *(h2*)&dst[i * 4 + 2] = b;
}

// ---------------- small GEMM body (TM x 128, BK=32), used for Q and out proj ----
template<int OUTF16, int TM, int AFP32>
__device__ __forceinline__ void gemm_body(
    const void* __restrict__ Ap, const _Float16* __restrict__ Bw,
    const float* __restrict__ bias, void* __restrict__ outp, float oscale,
    int bm, int bn)
{
    constexpr int MI = TM / 32;
    __shared__ alignas(16) _Float16 As[TM * 32];
    __shared__ alignas(16) _Float16 Bs[128 * 32];

    const int t    = threadIdx.x;
    const int lane = t & 63;
    const int wave = t >> 6;
    const int wm   = wave >> 1, wn = wave & 1;

    floatx4 acc[MI][4] = {};

    const int rowL = t >> 2;
    const int kcol = (t & 3) * 8;
    const _Float16* gB = Bw + (size_t)(bn * 128 + rowL) * CH + kcol;
    _Float16* lB = &Bs[rowL * 32 + kcol];

    const _Float16* gA16 = nullptr; _Float16* lA16 = nullptr;
    const float* gA32 = nullptr; _Float16* lA32 = nullptr;
    if constexpr (AFP32) {
        gA32 = (const float*)Ap + (size_t)(bm * TM + rowL) * CH + kcol;
        lA32 = &As[rowL * 32 + kcol];
    } else {
        gA16 = (const _Float16*)Ap + (size_t)(bm * TM + rowL) * CH + kcol;
        lA16 = &As[rowL * 32 + kcol];
    }

    const int r0 = lane & 15;
    const int ko = (lane >> 4) * 8;

    for (int kt = 0; kt < CH / 32; ++kt) {
        if constexpr (AFP32) {
            const float* ga = gA32 + kt * 32;
            float4 x0 = ((const float4*)ga)[0], x1 = ((const float4*)ga)[1];
            H8 o0;
            o0.p[0] = cvt2(x0.x, x0.y);
            o0.p[1] = cvt2(x0.z, x0.w);
            o0.p[2] = cvt2(x1.x, x1.y);
            o0.p[3] = cvt2(x1.z, x1.w);
            *(half8*)lA32 = o0.v;
        } else {
            const _Float16* a0 = gA16 + kt * 32;
            async16(a0, lA16);
        }
        const _Float16* b0 = gB + kt * 32;
        async16(b0,           lB);
        async16(b0 + 64 * CH, lB + 64 * 32);
        __syncthreads();

        half8 af[MI], bf[4];
        #pragma unroll
        for (int mi = 0; mi < MI; ++mi)
            af[mi] = *(const half8*)&As[(wm * (TM / 2) + mi * 16 + r0) * 32 + ko];
        #pragma unroll
        for (int ni = 0; ni < 4; ++ni)
            bf[ni] = *(const half8*)&Bs[(wn * 64 + ni * 16 + r0) * 32 + ko];
        #pragma unroll
        for (int mi = 0; mi < MI; ++mi)
            #pragma unroll
            for (int ni = 0; ni < 4; ++ni)
                acc[mi][ni] = __builtin_amdgcn_mfma_f32_16x16x32_f16(
                    af[mi], bf[ni], acc[mi][ni], 0, 0, 0);
        __syncthreads();
    }

    #pragma unroll
    for (int mi = 0; mi < MI; ++mi) {
        #pragma unroll
        for (int ni = 0; ni < 4; ++ni) {
            const int col = bn * 128 + wn * 64 + ni * 16 + (lane & 15);
            const float bv = bias[col];
            #pragma unroll
            for (int r = 0; r < 4; ++r) {
                const int row = bm * TM + wm * (TM / 2) + mi * 16 + (lane >> 4) * 4 + r;
                const float v = (acc[mi][ni][r] + bv) * oscale;
                if (OUTF16) ((_Float16*)outp)[(size_t)row * CH + col] = (_Float16)v;
                else        ((float*)outp)[(size_t)row * CH + col]    = v;
            }
        }
    }
}

template<int OUTF16, int TM, int AFP32>
__global__ __launch_bounds__(256) void gemm_k(
    const void* __restrict__ A, const _Float16* __restrict__ Bw,
    const float* __restrict__ bias, void* __restrict__ outp, float oscale)
{
    gemm_body<OUTF16, TM, AFP32>(A, Bw, bias, outp, oscale, blockIdx.x, blockIdx.y);
}

// ---------------- K/V projection GEMM: fp32 A staged to LDS via global_load_lds,
// converted in-register after ds_read. Swizzled (rule #21: linear LDS dest,
// inverse-swizzled per-lane global source, swizzled fragment read).
// 128x128 tile, BK=32, 256 threads. Grid (bn=4, bm=128, z=2).
__global__ __launch_bounds__(256) void gemm_kv(
    const float* __restrict__ keyp, const float* __restrict__ valp,
    const _Float16* __restrict__ w16, const float* __restrict__ bIn,
    _Float16* __restrict__ k16, _Float16* __restrict__ v16)
{
    const int z = blockIdx.z;
    const char*     Ab   = (const char*)(z ? valp : keyp);
    const char*     Bb   = (const char*)(w16 + (size_t)(z ? 1024 : 512) * 512);
    const float*    bias = bIn + (z ? 1024 : 512);
    _Float16*       outp = z ? v16 : k16;
    const int bn = blockIdx.x, bm = blockIdx.y;

    __shared__ alignas(16) float    As[128 * 32];   // fp32 A tile, 16 KB
    __shared__ alignas(16) _Float16 Bs[128 * 32];   // fp16 B tile, 8 KB

    const int t    = threadIdx.x;
    const int lane = t & 63;
    const int wave = t >> 6;
    const int wm   = wave >> 1, wn = wave & 1;

    floatx4 acc[4][4] = {};

    // ---- staging addresses (computed once)
    // A: 1024 granules (16B). LDS slot G = i*256+t (linear). Source granule
    // g = (G&7) ^ (row&7) within row G>>3  -> read side XORs the same way.
    uint32_t aoff[4]; char* alds[4];
    #pragma unroll
    for (int i = 0; i < 4; ++i) {
        const int G   = i * 256 + t;
        const int row = G >> 3;
        const int g   = (G & 7) ^ (row & 7);
        aoff[i] = (uint32_t)((bm * 128 + row) * 2048 + g * 16);
        alds[i] = (char*)As + (size_t)G * 16;
    }
    // B: 512 granules; row = 4 granules (64B). Swizzle over row-pairs:
    // slot G holds source (row = super*2 + (sgg>>2), g = sgg&3), sgg = (G&7)^(super&7).
    uint32_t boff[2]; char* blds[2];
    #pragma unroll
    for (int j = 0; j < 2; ++j) {
        const int G     = j * 256 + t;
        const int super = G >> 3;
        const int sgg   = (G & 7) ^ (super & 7);
        const int row   = super * 2 + (sgg >> 2);
        const int g     = sgg & 3;
        boff[j] = (uint32_t)((bn * 128 + row) * 1024 + g * 16);
        blds[j] = (char*)Bs + (size_t)G * 16;
    }

    const int r0  = lane & 15;
    const int hi  = lane >> 4;
    const int swz = r0 & 7;

    for (int kt = 0; kt < 16; ++kt) {
        #pragma unroll
        for (int i = 0; i < 4; ++i) async16(Ab + aoff[i] + kt * 128, alds[i]);
        #pragma unroll
        for (int j = 0; j < 2; ++j) async16(Bb + boff[j] + kt * 64, blds[j]);
        __syncthreads();

        half8 af[4], bf[4];
        #pragma unroll
        for (int mi = 0; mi < 4; ++mi) {
            const int row = wm * 64 + mi * 16 + r0;          // row&7 == swz
            const float4 x0 = *(const float4*)((const char*)As + row * 128 + (((hi * 2)     ^ swz) * 16));
            const float4 x1 = *(const float4*)((const char*)As + row * 128 + (((hi * 2 + 1) ^ swz) * 16));
            H8 o;
            o.p[0] = cvt2(x0.x, x0.y);
            o.p[1] = cvt2(x0.z, x0.w);
            o.p[2] = cvt2(x1.x, x1.y);
            o.p[3] = cvt2(x1.z, x1.w);
            af[mi] = o.v;
        }
        #pragma unroll
        for (int ni = 0; ni < 4; ++ni) {
            const int row   = wn * 64 + ni * 16 + r0;
            const int super = row >> 1;
            const int vv    = ((row & 1) * 4 + hi) ^ (super & 7);
            bf[ni] = *(const half8*)((const char*)Bs + super * 128 + vv * 16);
        }
        #pragma unroll
        for (int mi = 0; mi < 4; ++mi)
            #pragma unroll
            for (int ni = 0; ni < 4; ++ni)
                acc[mi][ni] = __builtin_amdgcn_mfma_f32_16x16x32_f16(
                    af[mi], bf[ni], acc[mi][ni], 0, 0, 0);
        __syncthreads();
    }

    #pragma unroll
    for (int mi = 0; mi < 4; ++mi) {
        #pragma unroll
        for (int ni = 0; ni < 4; ++ni) {
            const int col = bn * 128 + wn * 64 + ni * 16 + (lane & 15);
            const float bv = bias[col];
            #pragma unroll
            for (int r = 0; r < 4; ++r) {
                const int row = bm * 128 + wm * 64 + mi * 16 + (lane >> 4) * 4 + r;
                outp[(size_t)row * CH + col] = (_Float16)(acc[mi][ni][r] + bv);
            }
        }
    }
}

// ---------------- local attention: one block (256 thr) per query ----------------
__global__ __launch_bounds__(256) void attn_kernel(
    const _Float16* __restrict__ q16, const _Float16* __restrict__ k16,
    const _Float16* __restrict__ v16, const int* __restrict__ ipair,
    const int* __restrict__ ibatch, const int* __restrict__ kcnt,
    _Float16* __restrict__ op16, float* __restrict__ aout)
{
    __shared__ uint32_t vmask[LNB];       // row byte-offset | (masked<<31)
    __shared__ float    pls[LNB * 9];     // logits -> probs (stride 9)
    __shared__ __half2  pph[LNB * 9];     // probs pre-packed {p,p} fp16
    __shared__ float    part[4][CH];      // per-wave PV partials

    const int t = threadIdx.x;
    // XCD swizzle: batch b = n/512 -> XCD b (one batch's K+V fp16 fits one L2)
    const int n = ((blockIdx.x & 7) << 9) | (blockIdx.x >> 3);

    if (t < LNB) {
        const int idx = ipair[(size_t)n * LNB + t];
        const int b   = ibatch[n];
        int off = 0;
        for (int i = 0; i < b; ++i) off += kcnt[i];
        const uint32_t vo = (uint32_t)((idx < 0 ? 0 : (idx + off)) * (CH * 2));
        vmask[t] = vo | (idx < 0 ? 0x80000000u : 0u);
    }
    __syncthreads();

    const int lane = t & 63, wv = t >> 6;
    const int h    = lane >> 3;           // head for this lane
    const int l0   = wv * 24;             // wave's contiguous l-chunk

    // ---- phase 1: logits. lane owns dims [lane*8, +8); octet = one head.
    {
        const half8 qv = *(const half8*)(q16 + (size_t)n * CH + lane * 8);
        H8 qu; qu.v = qv;
        const char* kbase = (const char*)k16 + lane * 16;
        const int4* vb = (const int4*)&vmask[l0];
        for (int g = 0; g < 3; ++g) {
            const int4 w0 = vb[2 * g], w1 = vb[2 * g + 1];
            uint32_t vm8[8] = {(uint32_t)w0.x, (uint32_t)w0.y, (uint32_t)w0.z, (uint32_t)w0.w,
                               (uint32_t)w1.x, (uint32_t)w1.y, (uint32_t)w1.z, (uint32_t)w1.w};
            #pragma unroll
            for (int j = 0; j < 8; ++j) {
                const uint32_t vms = __builtin_amdgcn_readfirstlane(vm8[j]);
                H8 ku; ku.v = *(const half8*)(kbase + (vms & 0x7fffffffu));
                float acc = 0.f;
                #pragma unroll
                for (int u = 0; u < 4; ++u)
                    acc = __builtin_amdgcn_fdot2(qu.p[u], ku.p[u], acc, false);
                acc = octet_sum(acc);
                if ((lane & 7) == 0)
                    pls[(l0 + g * 8 + j) * 9 + h] = (vms & 0x80000000u) ? -1e30f : acc;
            }
        }
    }
    __syncthreads();

    // ---- phase 2: softmax over L per head (hh = t>>5, j = t&31)
    {
        const int hh = t >> 5, j = t & 31;
        const float v0 = pls[j * 9 + hh];
        const float v1 = pls[(j + 32) * 9 + hh];
        const float v2 = pls[(j + 64) * 9 + hh];
        float m = fmaxf(v0, fmaxf(v1, v2));
        #pragma unroll
        for (int s = 16; s >= 1; s >>= 1) m = fmaxf(m, __shfl_xor(m, s, 32));
        const float e0 = __expf(v0 - m), e1 = __expf(v1 - m), e2 = __expf(v2 - m);
        float ssum = e0 + e1 + e2;
        #pragma unroll
        for (int s = 16; s >= 1; s >>= 1) ssum += __shfl_xor(ssum, s, 32);
        const float rinv = 1.0f / ssum;
        const float p0 = e0 * rinv, p1 = e1 * rinv, p2 = e2 * rinv;
        pls[j * 9 + hh]        = p0;
        pls[(j + 32) * 9 + hh] = p1;
        pls[(j + 64) * 9 + hh] = p2;
        pph[j * 9 + hh]        = __half2half2(__float2half_rn(p0));
        pph[(j + 32) * 9 + hh] = __half2half2(__float2half_rn(p1));
        pph[(j + 64) * 9 + hh] = __half2half2(__float2half_rn(p2));
    }
    __syncthreads();

    // ---- attn_mean (output 1)
    if (t < LNB) {
        float s = 0.f;
        #pragma unroll
        for (int u = 0; u < NH; ++u) s += pls[t * 9 + u];
        aout[(size_t)n * LNB + t] = s * (1.0f / NH);
    }

    // ---- phase 3: PV. wave owns l in [l0, l0+24), lane owns 8 dims.
    {
        float accf[8] = {};
        const char* vbase = (const char*)v16 + lane * 16;
        const int4* vb = (const int4*)&vmask[l0];
        const __half2 hz = __half2half2(__float2half_rn(0.f));
        for (int g = 0; g < 3; ++g) {
            const int4 w0 = vb[2 * g], w1 = vb[2 * g + 1];
            uint32_t vm8[8] = {(uint32_t)w0.x, (uint32_t)w0.y, (uint32_t)w0.z, (uint32_t)w0.w,
                               (uint32_t)w1.x, (uint32_t)w1.y, (uint32_t)w1.z, (uint32_t)w1.w};
            __half2 a0 = hz, a1 = hz, a2 = hz, a3 = hz;
            #pragma unroll
            for (int j = 0; j < 8; ++j) {
                const uint32_t vms = __builtin_amdgcn_readfirstlane(vm8[j]);
                const half8 vv = *(const half8*)(vbase + (vms & 0x7fffffffu));
                union { half8 v; __half2 q[4]; } vu; vu.v = vv;
                const __half2 pp = pph[(l0 + g * 8 + j) * 9 + h];
                a0 = __hfma2(pp, vu.q[0], a0);
                a1 = __hfma2(pp, vu.q[1], a1);
                a2 = __hfma2(pp, vu.q[2], a2);
                a3 = __hfma2(pp, vu.q[3], a3);
            }
            float2 f;
            f = __half22float2(a0); accf[0] += f.x; accf[1] += f.y;
            f = __half22float2(a1); accf[2] += f.x; accf[3] += f.y;
            f = __half22float2(a2); accf[4] += f.x; accf[5] += f.y;
            f = __half22float2(a3); accf[6] += f.x; accf[7] += f.y;
        }
        floatx4 lo, hi;
        #pragma unroll
        for (int u = 0; u < 4; ++u) { lo[u] = accf[u]; hi[u] = accf[u + 4]; }
        *(floatx4*)&part[wv][lane * 8]     = lo;
        *(floatx4*)&part[wv][lane * 8 + 4] = hi;
    }
    __syncthreads();

    // ---- final cross-wave reduce: thread t owns dims 2t, 2t+1
    {
        const int c = t * 2;
        floatx2 s = *(const floatx2*)&part[0][c];
        #pragma unroll
        for (int w = 1; w < 4; ++w) {
            floatx2 pw = *(const floatx2*)&part[w][c];
            s[0] += pw[0]; s[1] += pw[1];
        }
        h2 o; o[0] = (_Float16)s[0]; o[1] = (_Float16)s[1];
        *(h2*)&op16[(size_t)n * CH + c] = o;
    }
}

extern "C" void kernel_launch(void* const* d_in, const int* in_sizes, int n_in,
                              void* d_out, int out_size, void* d_ws, size_t ws_size,
                              hipStream_t stream)
{
    const float* query = (const float*)d_in[0];
    const float* key   = (const float*)d_in[1];
    const float* value = (const float*)d_in[2];
    const int*   ipair = (const int*)d_in[3];
    const int*   kcnt  = (const int*)d_in[5];
    const int*   ibat  = (const int*)d_in[6];
    const float* wIn   = (const float*)d_in[7];
    const float* bIn   = (const float*)d_in[8];
    const float* wOut  = (const float*)d_in[9];
    const float* bOut  = (const float*)d_in[10];

    float* out  = (float*)d_out;
    float* aout = out + (size_t)N_Q * CH;

    char* ws = (char*)d_ws;
    _Float16* w16  = (_Float16*)(ws);                // in-proj weights fp16 (1.5MB)
    _Float16* wo16 = (_Float16*)(ws + 1572864);      // out-proj weights fp16 (contiguous)
    _Float16* q16  = (_Float16*)(ws + 2097152);      // 4MB
    _Float16* k16  = (_Float16*)(ws + 6291456);      // 16MB
    _Float16* v16  = (_Float16*)(ws + 23068672);     // 16MB
    _Float16* op16 = (_Float16*)(ws + 39845888);     // 4MB

    // one fused weight convert (wIn ++ wOut -> w16 ++ wo16)
    cvt_weights<<<1024, 256, 0, stream>>>(wIn, wOut, w16);

    // Q projection with fused fp32->fp16 A staging (scaling folded in)
    gemm_k<1, 64, 1><<<dim3(64, 4), 256, 0, stream>>>(query, w16, bIn, q16, 0.125f);

    // K/V projections: fp32 A via global_load_lds + in-register cvt, swizzled LDS
    gemm_kv<<<dim3(4, 128, 2), 256, 0, stream>>>(key, value, w16, bIn, k16, v16);

    attn_kernel<<<4096, 256, 0, stream>>>(q16, k16, v16, ipair, ibat, kcnt, op16, aout);

    gemm_k<0, 64, 0><<<dim3(64, 4), 256, 0, stream>>>(op16, wo16, bOut, d_out, 1.0f);
}

// Round 7
// 100.746 us; speedup vs baseline: 1.4234x; 1.1322x over previous
//
#include <hip/hip_runtime.h>
#include <hip/hip_fp16.h>
#include <cstdint>
#include <cstddef>

#define N_Q 4096
#define M_K 16384
#define LNB 96
#define CH  512
#define NH  8

typedef _Float16 half8  __attribute__((ext_vector_type(8)));
typedef _Float16 h2     __attribute__((ext_vector_type(2)));
typedef float    floatx4 __attribute__((ext_vector_type(4)));
typedef float    floatx2 __attribute__((ext_vector_type(2)));

union H8 { half8 v; h2 p[4]; };

__device__ __forceinline__ h2 cvt2(float a, float b) {
    return __builtin_bit_cast(h2, __builtin_amdgcn_cvt_pkrtz(a, b));
}

__device__ __forceinline__ void async16(const void* g, void* l) {
    __builtin_amdgcn_global_load_lds(
        (const __attribute__((address_space(1))) void*)g,
        (__attribute__((address_space(3))) void*)l, 16, 0, 0);
}

// DPP butterfly add over an 8-lane octet (pure VALU).
template<int CTRL>
__device__ __forceinline__ float dpp_addf(float x) {
    int xi = __builtin_bit_cast(int, x);
    int yi = __builtin_amdgcn_update_dpp(xi, xi, CTRL, 0xF, 0xF, false);
    return x + __builtin_bit_cast(float, yi);
}
__device__ __forceinline__ float octet_sum(float x) {
    x = dpp_addf<0x141>(x);   // row_half_mirror
    x = dpp_addf<0x4E>(x);    // quad xor2
    x = dpp_addf<0xB1>(x);    // quad xor1
    return x;
}

// ---------------- fused weight convert: wIn (786432 f) ++ wOut (262144 f) -> fp16
__global__ void cvt_weights(const float* __restrict__ wIn, const float* __restrict__ wOut,
                            _Float16* __restrict__ dst) {
    const size_t i = (size_t)blockIdx.x * blockDim.x + threadIdx.x;   // float4 index
    const float4 v = (i < 196608) ? ((const float4*)wIn)[i]
                                  : ((const float4*)wOut)[i - 196608];
    h2 a = cvt2(v.x, v.y);
    h2 b = cvt2(v.z, v.w);
    *(h2*)&dst[i * 4]     = a;
    *(h2*)&dst[i * 4 + 2] = b;
}

// ---------------- small GEMM body (TM x 128, BK=32), used for Q and out proj ----
template<int OUTF16, int TM, int AFP32>
__device__ __forceinline__ void gemm_body(
    const void* __restrict__ Ap, const _Float16* __restrict__ Bw,
    const float* __restrict__ bias, void* __restrict__ outp, float oscale,
    int bm, int bn)
{
    constexpr int MI = TM / 32;
    __shared__ alignas(16) _Float16 As[TM * 32];
    __shared__ alignas(16) _Float16 Bs[128 * 32];

    const int t    = threadIdx.x;
    const int lane = t & 63;
    const int wave = t >> 6;
    const int wm   = wave >> 1, wn = wave & 1;

    floatx4 acc[MI][4] = {};

    const int rowL = t >> 2;
    const int kcol = (t & 3) * 8;
    const _Float16* gB = Bw + (size_t)(bn * 128 + rowL) * CH + kcol;
    _Float16* lB = &Bs[rowL * 32 + kcol];

    const _Float16* gA16 = nullptr; _Float16* lA16 = nullptr;
    const float* gA32 = nullptr; _Float16* lA32 = nullptr;
    if constexpr (AFP32) {
        gA32 = (const float*)Ap + (size_t)(bm * TM + rowL) * CH + kcol;
        lA32 = &As[rowL * 32 + kcol];
    } else {
        gA16 = (const _Float16*)Ap + (size_t)(bm * TM + rowL) * CH + kcol;
        lA16 = &As[rowL * 32 + kcol];
    }

    const int r0 = lane & 15;
    const int ko = (lane >> 4) * 8;

    for (int kt = 0; kt < CH / 32; ++kt) {
        if constexpr (AFP32) {
            const float* ga = gA32 + kt * 32;
            float4 x0 = ((const float4*)ga)[0], x1 = ((const float4*)ga)[1];
            H8 o0;
            o0.p[0] = cvt2(x0.x, x0.y);
            o0.p[1] = cvt2(x0.z, x0.w);
            o0.p[2] = cvt2(x1.x, x1.y);
            o0.p[3] = cvt2(x1.z, x1.w);
            *(half8*)lA32 = o0.v;
        } else {
            const _Float16* a0 = gA16 + kt * 32;
            async16(a0, lA16);
        }
        const _Float16* b0 = gB + kt * 32;
        async16(b0,           lB);
        async16(b0 + 64 * CH, lB + 64 * 32);
        __syncthreads();

        half8 af[MI], bf[4];
        #pragma unroll
        for (int mi = 0; mi < MI; ++mi)
            af[mi] = *(const half8*)&As[(wm * (TM / 2) + mi * 16 + r0) * 32 + ko];
        #pragma unroll
        for (int ni = 0; ni < 4; ++ni)
            bf[ni] = *(const half8*)&Bs[(wn * 64 + ni * 16 + r0) * 32 + ko];
        #pragma unroll
        for (int mi = 0; mi < MI; ++mi)
            #pragma unroll
            for (int ni = 0; ni < 4; ++ni)
                acc[mi][ni] = __builtin_amdgcn_mfma_f32_16x16x32_f16(
                    af[mi], bf[ni], acc[mi][ni], 0, 0, 0);
        __syncthreads();
    }

    #pragma unroll
    for (int mi = 0; mi < MI; ++mi) {
        #pragma unroll
        for (int ni = 0; ni < 4; ++ni) {
            const int col = bn * 128 + wn * 64 + ni * 16 + (lane & 15);
            const float bv = bias[col];
            #pragma unroll
            for (int r = 0; r < 4; ++r) {
                const int row = bm * TM + wm * (TM / 2) + mi * 16 + (lane >> 4) * 4 + r;
                const float v = (acc[mi][ni][r] + bv) * oscale;
                if (OUTF16) ((_Float16*)outp)[(size_t)row * CH + col] = (_Float16)v;
                else        ((float*)outp)[(size_t)row * CH + col]    = v;
            }
        }
    }
}

// XCD-grouped decode: blocks sharing an A-tile (same bm, 4 bn's) land on ONE
// XCD (assumes hw round-robin bid%8 -> XCD) and are consecutive there.
// grid = NBM*4 linear; NBM % 8 == 0.
template<int OUTF16, int TM, int AFP32>
__global__ __launch_bounds__(256) void gemm_k(
    const void* __restrict__ A, const _Float16* __restrict__ Bw,
    const float* __restrict__ bias, void* __restrict__ outp, float oscale)
{
    const int bid = blockIdx.x;
    const int x   = bid & 7;
    const int i   = bid >> 3;
    const int bn  = i & 3;
    const int bm  = x + 8 * (i >> 2);
    gemm_body<OUTF16, TM, AFP32>(A, Bw, bias, outp, oscale, bm, bn);
}

// ---------------- K/V projection GEMM: fp32 A staged to LDS via global_load_lds,
// converted in-register after ds_read. Swizzled (rule #21). 128x128, BK=32.
// Linear grid 1024, XCD-grouped: bm = xcd + 8*group so all 4 bn-consumers of an
// A-tile share one XCD's L2 (kills the 2x HBM over-fetch seen in R6).
__global__ __launch_bounds__(256) void gemm_kv(
    const float* __restrict__ keyp, const float* __restrict__ valp,
    const _Float16* __restrict__ w16, const float* __restrict__ bIn,
    _Float16* __restrict__ k16, _Float16* __restrict__ v16)
{
    const int bid = blockIdx.x;
    const int x   = bid & 7;          // XCD
    const int i   = bid >> 3;         // 0..127
    const int bn  = i & 3;
    const int z   = (i >> 2) & 1;
    const int bm  = x + 8 * (i >> 3); // 0..127

    const char*     Ab   = (const char*)(z ? valp : keyp);
    const char*     Bb   = (const char*)(w16 + (size_t)(z ? 1024 : 512) * 512);
    const float*    bias = bIn + (z ? 1024 : 512);
    _Float16*       outp = z ? v16 : k16;

    __shared__ alignas(16) float    As[128 * 32];   // fp32 A tile, 16 KB
    __shared__ alignas(16) _Float16 Bs[128 * 32];   // fp16 B tile, 8 KB

    const int t    = threadIdx.x;
    const int lane = t & 63;
    const int wave = t >> 6;
    const int wm   = wave >> 1, wn = wave & 1;

    floatx4 acc[4][4] = {};

    // A: 1024 granules (16B). LDS slot G = i*256+t (linear). Source granule
    // g = (G&7) ^ (row&7) within row G>>3  -> read side XORs the same way.
    uint32_t aoff[4]; char* alds[4];
    #pragma unroll
    for (int q = 0; q < 4; ++q) {
        const int G   = q * 256 + t;
        const int row = G >> 3;
        const int g   = (G & 7) ^ (row & 7);
        aoff[q] = (uint32_t)((bm * 128 + row) * 2048 + g * 16);
        alds[q] = (char*)As + (size_t)G * 16;
    }
    // B: 512 granules; swizzle over row-pairs.
    uint32_t boff[2]; char* blds[2];
    #pragma unroll
    for (int q = 0; q < 2; ++q) {
        const int G     = q * 256 + t;
        const int super = G >> 3;
        const int sgg   = (G & 7) ^ (super & 7);
        const int row   = super * 2 + (sgg >> 2);
        const int g     = sgg & 3;
        boff[q] = (uint32_t)((bn * 128 + row) * 1024 + g * 16);
        blds[q] = (char*)Bs + (size_t)G * 16;
    }

    const int r0  = lane & 15;
    const int hi  = lane >> 4;
    const int swz = r0 & 7;

    for (int kt = 0; kt < 16; ++kt) {
        #pragma unroll
        for (int q = 0; q < 4; ++q) async16(Ab + aoff[q] + kt * 128, alds[q]);
        #pragma unroll
        for (int q = 0; q < 2; ++q) async16(Bb + boff[q] + kt * 64, blds[q]);
        __syncthreads();

        half8 af[4], bf[4];
        #pragma unroll
        for (int mi = 0; mi < 4; ++mi) {
            const int row = wm * 64 + mi * 16 + r0;          // row&7 == swz
            const float4 x0 = *(const float4*)((const char*)As + row * 128 + (((hi * 2)     ^ swz) * 16));
            const float4 x1 = *(const float4*)((const char*)As + row * 128 + (((hi * 2 + 1) ^ swz) * 16));
            H8 o;
            o.p[0] = cvt2(x0.x, x0.y);
            o.p[1] = cvt2(x0.z, x0.w);
            o.p[2] = cvt2(x1.x, x1.y);
            o.p[3] = cvt2(x1.z, x1.w);
            af[mi] = o.v;
        }
        #pragma unroll
        for (int ni = 0; ni < 4; ++ni) {
            const int row   = wn * 64 + ni * 16 + r0;
            const int super = row >> 1;
            const int vv    = ((row & 1) * 4 + hi) ^ (super & 7);
            bf[ni] = *(const half8*)((const char*)Bs + super * 128 + vv * 16);
        }
        #pragma unroll
        for (int mi = 0; mi < 4; ++mi)
            #pragma unroll
            for (int ni = 0; ni < 4; ++ni)
                acc[mi][ni] = __builtin_amdgcn_mfma_f32_16x16x32_f16(
                    af[mi], bf[ni], acc[mi][ni], 0, 0, 0);
        __syncthreads();
    }

    #pragma unroll
    for (int mi = 0; mi < 4; ++mi) {
        #pragma unroll
        for (int ni = 0; ni < 4; ++ni) {
            const int col = bn * 128 + wn * 64 + ni * 16 + (lane & 15);
            const float bv = bias[col];
            #pragma unroll
            for (int r = 0; r < 4; ++r) {
                const int row = bm * 128 + wm * 64 + mi * 16 + (lane >> 4) * 4 + r;
                outp[(size_t)row * CH + col] = (_Float16)(acc[mi][ni][r] + bv);
            }
        }
    }
}

// ---------------- local attention: one block (256 thr) per query ----------------
__global__ __launch_bounds__(256) void attn_kernel(
    const _Float16* __restrict__ q16, const _Float16* __restrict__ k16,
    const _Float16* __restrict__ v16, const int* __restrict__ ipair,
    const int* __restrict__ ibatch, const int* __restrict__ kcnt,
    _Float16* __restrict__ op16, float* __restrict__ aout)
{
    __shared__ uint32_t vmask[LNB];       // row byte-offset | (masked<<31)
    __shared__ float    pls[LNB * 9];     // logits -> probs (stride 9)
    __shared__ __half2  pph[LNB * 9];     // probs pre-packed {p,p} fp16
    __shared__ float    part[4][CH];      // per-wave PV partials

    const int t = threadIdx.x;
    // XCD swizzle: batch b = n/512 -> XCD b (one batch's K+V fp16 fits one L2)
    const int n = ((blockIdx.x & 7) << 9) | (blockIdx.x >> 3);

    if (t < LNB) {
        const int idx = ipair[(size_t)n * LNB + t];
        const int b   = ibatch[n];
        int off = 0;
        for (int i = 0; i < b; ++i) off += kcnt[i];
        const uint32_t vo = (uint32_t)((idx < 0 ? 0 : (idx + off)) * (CH * 2));
        vmask[t] = vo | (idx < 0 ? 0x80000000u : 0u);
    }
    __syncthreads();

    const int lane = t & 63, wv = t >> 6;
    const int h    = lane >> 3;           // head for this lane
    const int l0   = wv * 24;             // wave's contiguous l-chunk

    // ---- phase 1: logits. lane owns dims [lane*8, +8); octet = one head.
    {
        const half8 qv = *(const half8*)(q16 + (size_t)n * CH + lane * 8);
        H8 qu; qu.v = qv;
        const char* kbase = (const char*)k16 + lane * 16;
        const int4* vb = (const int4*)&vmask[l0];
        for (int g = 0; g < 3; ++g) {
            const int4 w0 = vb[2 * g], w1 = vb[2 * g + 1];
            uint32_t vm8[8] = {(uint32_t)w0.x, (uint32_t)w0.y, (uint32_t)w0.z, (uint32_t)w0.w,
                               (uint32_t)w1.x, (uint32_t)w1.y, (uint32_t)w1.z, (uint32_t)w1.w};
            #pragma unroll
            for (int j = 0; j < 8; ++j) {
                const uint32_t vms = __builtin_amdgcn_readfirstlane(vm8[j]);
                H8 ku; ku.v = *(const half8*)(kbase + (vms & 0x7fffffffu));
                float acc = 0.f;
                #pragma unroll
                for (int u = 0; u < 4; ++u)
                    acc = __builtin_amdgcn_fdot2(qu.p[u], ku.p[u], acc, false);
                acc = octet_sum(acc);
                if ((lane & 7) == 0)
                    pls[(l0 + g * 8 + j) * 9 + h] = (vms & 0x80000000u) ? -1e30f : acc;
            }
        }
    }
    __syncthreads();

    // ---- phase 2: softmax over L per head (hh = t>>5, j = t&31)
    {
        const int hh = t >> 5, j = t & 31;
        const float v0 = pls[j * 9 + hh];
        const float v1 = pls[(j + 32) * 9 + hh];
        const float v2 = pls[(j + 64) * 9 + hh];
        float m = fmaxf(v0, fmaxf(v1, v2));
        #pragma unroll
        for (int s = 16; s >= 1; s >>= 1) m = fmaxf(m, __shfl_xor(m, s, 32));
        const float e0 = __expf(v0 - m), e1 = __expf(v1 - m), e2 = __expf(v2 - m);
        float ssum = e0 + e1 + e2;
        #pragma unroll
        for (int s = 16; s >= 1; s >>= 1) ssum += __shfl_xor(ssum, s, 32);
        const float rinv = 1.0f / ssum;
        const float p0 = e0 * rinv, p1 = e1 * rinv, p2 = e2 * rinv;
        pls[j * 9 + hh]        = p0;
        pls[(j + 32) * 9 + hh] = p1;
        pls[(j + 64) * 9 + hh] = p2;
        pph[j * 9 + hh]        = __half2half2(__float2half_rn(p0));
        pph[(j + 32) * 9 + hh] = __half2half2(__float2half_rn(p1));
        pph[(j + 64) * 9 + hh] = __half2half2(__float2half_rn(p2));
    }
    __syncthreads();

    // ---- attn_mean (output 1)
    if (t < LNB) {
        float s = 0.f;
        #pragma unroll
        for (int u = 0; u < NH; ++u) s += pls[t * 9 + u];
        aout[(size_t)n * LNB + t] = s * (1.0f / NH);
    }

    // ---- phase 3: PV. wave owns l in [l0, l0+24), lane owns 8 dims.
    {
        float accf[8] = {};
        const char* vbase = (const char*)v16 + lane * 16;
        const int4* vb = (const int4*)&vmask[l0];
        const __half2 hz = __half2half2(__float2half_rn(0.f));
        for (int g = 0; g < 3; ++g) {
            const int4 w0 = vb[2 * g], w1 = vb[2 * g + 1];
            uint32_t vm8[8] = {(uint32_t)w0.x, (uint32_t)w0.y, (uint32_t)w0.z, (uint32_t)w0.w,
                               (uint32_t)w1.x, (uint32_t)w1.y, (uint32_t)w1.z, (uint32_t)w1.w};
            __half2 a0 = hz, a1 = hz, a2 = hz, a3 = hz;
            #pragma unroll
            for (int j = 0; j < 8; ++j) {
                const uint32_t vms = __builtin_amdgcn_readfirstlane(vm8[j]);
                const half8 vv = *(const half8*)(vbase + (vms & 0x7fffffffu));
                union { half8 v; __half2 q[4]; } vu; vu.v = vv;
                const __half2 pp = pph[(l0 + g * 8 + j) * 9 + h];
                a0 = __hfma2(pp, vu.q[0], a0);
                a1 = __hfma2(pp, vu.q[1], a1);
                a2 = __hfma2(pp, vu.q[2], a2);
                a3 = __hfma2(pp, vu.q[3], a3);
            }
            float2 f;
            f = __half22float2(a0); accf[0] += f.x; accf[1] += f.y;
            f = __half22float2(a1); accf[2] += f.x; accf[3] += f.y;
            f = __half22float2(a2); accf[4] += f.x; accf[5] += f.y;
            f = __half22float2(a3); accf[6] += f.x; accf[7] += f.y;
        }
        floatx4 lo, hi;
        #pragma unroll
        for (int u = 0; u < 4; ++u) { lo[u] = accf[u]; hi[u] = accf[u + 4]; }
        *(floatx4*)&part[wv][lane * 8]     = lo;
        *(floatx4*)&part[wv][lane * 8 + 4] = hi;
    }
    __syncthreads();

    // ---- final cross-wave reduce: thread t owns dims 2t, 2t+1
    {
        const int c = t * 2;
        floatx2 s = *(const floatx2*)&part[0][c];
        #pragma unroll
        for (int w = 1; w < 4; ++w) {
            floatx2 pw = *(const floatx2*)&part[w][c];
            s[0] += pw[0]; s[1] += pw[1];
        }
        h2 o; o[0] = (_Float16)s[0]; o[1] = (_Float16)s[1];
        *(h2*)&op16[(size_t)n * CH + c] = o;
    }
}

extern "C" void kernel_launch(void* const* d_in, const int* in_sizes, int n_in,
                              void* d_out, int out_size, void* d_ws, size_t ws_size,
                              hipStream_t stream)
{
    const float* query = (const float*)d_in[0];
    const float* key   = (const float*)d_in[1];
    const float* value = (const float*)d_in[2];
    const int*   ipair = (const int*)d_in[3];
    const int*   kcnt  = (const int*)d_in[5];
    const int*   ibat  = (const int*)d_in[6];
    const float* wIn   = (const float*)d_in[7];
    const float* bIn   = (const float*)d_in[8];
    const float* wOut  = (const float*)d_in[9];
    const float* bOut  = (const float*)d_in[10];

    float* out  = (float*)d_out;
    float* aout = out + (size_t)N_Q * CH;

    char* ws = (char*)d_ws;
    _Float16* w16  = (_Float16*)(ws);                // in-proj weights fp16 (1.5MB)
    _Float16* wo16 = (_Float16*)(ws + 1572864);      // out-proj weights fp16 (contiguous)
    _Float16* q16  = (_Float16*)(ws + 2097152);      // 4MB
    _Float16* k16  = (_Float16*)(ws + 6291456);      // 16MB
    _Float16* v16  = (_Float16*)(ws + 23068672);     // 16MB
    _Float16* op16 = (_Float16*)(ws + 39845888);     // 4MB

    // one fused weight convert (wIn ++ wOut -> w16 ++ wo16)
    cvt_weights<<<1024, 256, 0, stream>>>(wIn, wOut, w16);

    // Q projection with fused fp32->fp16 A staging (scaling folded in)
    gemm_k<1, 64, 1><<<256, 256, 0, stream>>>(query, w16, bIn, q16, 0.125f);

    // K/V projections: fp32 A via global_load_lds + in-register cvt, swizzled LDS,
    // XCD-grouped so A-tile consumers share one L2
    gemm_kv<<<1024, 256, 0, stream>>>(key, value, w16, bIn, k16, v16);

    attn_kernel<<<4096, 256, 0, stream>>>(q16, k16, v16, ipair, ibat, kcnt, op16, aout);

    gemm_k<0, 64, 0><<<256, 256, 0, stream>>>(op16, wo16, bOut, d_out, 1.0f);
}

// Round 8
// 99.944 us; speedup vs baseline: 1.4349x; 1.0080x over previous
//
#include <hip/hip_runtime.h>
#include <hip/hip_fp16.h>
#include <cstdint>
#include <cstddef>

#define N_Q 4096
#define M_K 16384
#define LNB 96
#define CH  512
#define NH  8

typedef _Float16 half8  __attribute__((ext_vector_type(8)));
typedef _Float16 h2     __attribute__((ext_vector_type(2)));
typedef float    floatx4 __attribute__((ext_vector_type(4)));
typedef float    floatx2 __attribute__((ext_vector_type(2)));

union H8 { half8 v; h2 p[4]; };

__device__ __forceinline__ h2 cvt2(float a, float b) {
    return __builtin_bit_cast(h2, __builtin_amdgcn_cvt_pkrtz(a, b));
}

__device__ __forceinline__ void async16(const void* g, void* l) {
    __builtin_amdgcn_global_load_lds(
        (const __attribute__((address_space(1))) void*)g,
        (__attribute__((address_space(3))) void*)l, 16, 0, 0);
}

// DPP butterfly add over an 8-lane octet (pure VALU).
template<int CTRL>
__device__ __forceinline__ float dpp_addf(float x) {
    int xi = __builtin_bit_cast(int, x);
    int yi = __builtin_amdgcn_update_dpp(xi, xi, CTRL, 0xF, 0xF, false);
    return x + __builtin_bit_cast(float, yi);
}
__device__ __forceinline__ float octet_sum(float x) {
    x = dpp_addf<0x141>(x);   // row_half_mirror
    x = dpp_addf<0x4E>(x);    // quad xor2
    x = dpp_addf<0xB1>(x);    // quad xor1
    return x;
}

// ---------------- fused weight convert: wIn (786432 f) ++ wOut (262144 f) -> fp16
__global__ void cvt_weights(const float* __restrict__ wIn, const float* __restrict__ wOut,
                            _Float16* __restrict__ dst) {
    const size_t i = (size_t)blockIdx.x * blockDim.x + threadIdx.x;   // float4 index
    const float4 v = (i < 196608) ? ((const float4*)wIn)[i]
                                  : ((const float4*)wOut)[i - 196608];
    h2 a = cvt2(v.x, v.y);
    h2 b = cvt2(v.z, v.w);
    *(h2*)&dst[i * 4]     = a;
    *(h2*)&dst[i * 4 + 2] = b;
}

// ---------------- small GEMM body (TM x 128, BK=32), used for Q and out proj ----
template<int OUTF16, int TM, int AFP32>
__device__ __forceinline__ void gemm_body(
    const void* __restrict__ Ap, const _Float16* __restrict__ Bw,
    const float* __restrict__ bias, void* __restrict__ outp, float oscale,
    int bm, int bn)
{
    constexpr int MI = TM / 32;
    __shared__ alignas(16) _Float16 As[TM * 32];
    __shared__ alignas(16) _Float16 Bs[128 * 32];

    const int t    = threadIdx.x;
    const int lane = t & 63;
    const int wave = t >> 6;
    const int wm   = wave >> 1, wn = wave & 1;

    floatx4 acc[MI][4] = {};

    const int rowL = t >> 2;
    const int kcol = (t & 3) * 8;
    const _Float16* gB = Bw + (size_t)(bn * 128 + rowL) * CH + kcol;
    _Float16* lB = &Bs[rowL * 32 + kcol];

    const _Float16* gA16 = nullptr; _Float16* lA16 = nullptr;
    const float* gA32 = nullptr; _Float16* lA32 = nullptr;
    if constexpr (AFP32) {
        gA32 = (const float*)Ap + (size_t)(bm * TM + rowL) * CH + kcol;
        lA32 = &As[rowL * 32 + kcol];
    } else {
        gA16 = (const _Float16*)Ap + (size_t)(bm * TM + rowL) * CH + kcol;
        lA16 = &As[rowL * 32 + kcol];
    }

    const int r0 = lane & 15;
    const int ko = (lane >> 4) * 8;

    for (int kt = 0; kt < CH / 32; ++kt) {
        if constexpr (AFP32) {
            const float* ga = gA32 + kt * 32;
            float4 x0 = ((const float4*)ga)[0], x1 = ((const float4*)ga)[1];
            H8 o0;
            o0.p[0] = cvt2(x0.x, x0.y);
            o0.p[1] = cvt2(x0.z, x0.w);
            o0.p[2] = cvt2(x1.x, x1.y);
            o0.p[3] = cvt2(x1.z, x1.w);
            *(half8*)lA32 = o0.v;
        } else {
            const _Float16* a0 = gA16 + kt * 32;
            async16(a0, lA16);
        }
        const _Float16* b0 = gB + kt * 32;
        async16(b0,           lB);
        async16(b0 + 64 * CH, lB + 64 * 32);
        __syncthreads();

        half8 af[MI], bf[4];
        #pragma unroll
        for (int mi = 0; mi < MI; ++mi)
            af[mi] = *(const half8*)&As[(wm * (TM / 2) + mi * 16 + r0) * 32 + ko];
        #pragma unroll
        for (int ni = 0; ni < 4; ++ni)
            bf[ni] = *(const half8*)&Bs[(wn * 64 + ni * 16 + r0) * 32 + ko];
        #pragma unroll
        for (int mi = 0; mi < MI; ++mi)
            #pragma unroll
            for (int ni = 0; ni < 4; ++ni)
                acc[mi][ni] = __builtin_amdgcn_mfma_f32_16x16x32_f16(
                    af[mi], bf[ni], acc[mi][ni], 0, 0, 0);
        __syncthreads();
    }

    #pragma unroll
    for (int mi = 0; mi < MI; ++mi) {
        #pragma unroll
        for (int ni = 0; ni < 4; ++ni) {
            const int col = bn * 128 + wn * 64 + ni * 16 + (lane & 15);
            const float bv = bias[col];
            #pragma unroll
            for (int r = 0; r < 4; ++r) {
                const int row = bm * TM + wm * (TM / 2) + mi * 16 + (lane >> 4) * 4 + r;
                const float v = (acc[mi][ni][r] + bv) * oscale;
                if (OUTF16) ((_Float16*)outp)[(size_t)row * CH + col] = (_Float16)v;
                else        ((float*)outp)[(size_t)row * CH + col]    = v;
            }
        }
    }
}

// XCD-grouped decode: blocks sharing an A-tile (same bm, 4 bn's) land on ONE XCD.
template<int OUTF16, int TM, int AFP32>
__global__ __launch_bounds__(256) void gemm_k(
    const void* __restrict__ A, const _Float16* __restrict__ Bw,
    const float* __restrict__ bias, void* __restrict__ outp, float oscale)
{
    const int bid = blockIdx.x;
    const int x   = bid & 7;
    const int i   = bid >> 3;
    const int bn  = i & 3;
    const int bm  = x + 8 * (i >> 2);
    gemm_body<OUTF16, TM, AFP32>(A, Bw, bias, outp, oscale, bm, bn);
}

// ---------------- K/V projection GEMM, double-buffered (T3 minimum 2-phase) ----
// fp32 A staged direct to LDS (global_load_lds), cvt after ds_read. Swizzled per
// rule #21. 128x128, BK=32, prefetch-ahead-1, raw s_barrier + asm vmcnt(0)
// AFTER the compute phase (latency hidden under 16 MFMA + cvt).
#define KV_STAGE(AS, BS, KT) do {                                               \
    _Pragma("unroll")                                                           \
    for (int q = 0; q < 4; ++q)                                                 \
        async16(Ab + aoff[q] + (KT) * 128, (char*)(AS) + (q * 256 + t) * 16);   \
    _Pragma("unroll")                                                           \
    for (int q = 0; q < 2; ++q)                                                 \
        async16(Bb + boff[q] + (KT) * 64,  (char*)(BS) + (q * 256 + t) * 16);   \
    __builtin_amdgcn_sched_barrier(0);                                          \
} while (0)

#define KV_COMPUTE(AS, BS) do {                                                 \
    half8 af[4], bf[4];                                                         \
    _Pragma("unroll")                                                           \
    for (int mi = 0; mi < 4; ++mi) {                                            \
        const int row = wm * 64 + mi * 16 + r0;                                 \
        const float4 x0 = *(const float4*)((const char*)(AS) + row * 128 + (((hi * 2)     ^ swz) * 16)); \
        const float4 x1 = *(const float4*)((const char*)(AS) + row * 128 + (((hi * 2 + 1) ^ swz) * 16)); \
        H8 o;                                                                   \
        o.p[0] = cvt2(x0.x, x0.y);                                              \
        o.p[1] = cvt2(x0.z, x0.w);                                              \
        o.p[2] = cvt2(x1.x, x1.y);                                              \
        o.p[3] = cvt2(x1.z, x1.w);                                              \
        af[mi] = o.v;                                                           \
    }                                                                           \
    _Pragma("unroll")                                                           \
    for (int ni = 0; ni < 4; ++ni) {                                            \
        const int row   = wn * 64 + ni * 16 + r0;                               \
        const int super = row >> 1;                                             \
        const int vv    = ((row & 1) * 4 + hi) ^ (super & 7);                   \
        bf[ni] = *(const half8*)((const char*)(BS) + super * 128 + vv * 16);    \
    }                                                                           \
    _Pragma("unroll")                                                           \
    for (int mi = 0; mi < 4; ++mi)                                              \
        _Pragma("unroll")                                                       \
        for (int ni = 0; ni < 4; ++ni)                                          \
            acc[mi][ni] = __builtin_amdgcn_mfma_f32_16x16x32_f16(               \
                af[mi], bf[ni], acc[mi][ni], 0, 0, 0);                          \
} while (0)

#define KV_SYNC() do {                                                          \
    asm volatile("s_waitcnt vmcnt(0)" ::: "memory");                            \
    __builtin_amdgcn_s_barrier();                                               \
    __builtin_amdgcn_sched_barrier(0);                                          \
} while (0)

__global__ __launch_bounds__(256) void gemm_kv(
    const float* __restrict__ keyp, const float* __restrict__ valp,
    const _Float16* __restrict__ w16, const float* __restrict__ bIn,
    _Float16* __restrict__ k16, _Float16* __restrict__ v16)
{
    const int bid = blockIdx.x;
    const int x   = bid & 7;          // XCD
    const int i   = bid >> 3;         // 0..127
    const int bn  = i & 3;
    const int z   = (i >> 2) & 1;
    const int bm  = x + 8 * (i >> 3); // 0..127

    const char*     Ab   = (const char*)(z ? valp : keyp);
    const char*     Bb   = (const char*)(w16 + (size_t)(z ? 1024 : 512) * 512);
    const float*    bias = bIn + (z ? 1024 : 512);
    _Float16*       outp = z ? v16 : k16;

    __shared__ alignas(16) float    As0[128 * 32];   // 16 KB
    __shared__ alignas(16) float    As1[128 * 32];   // 16 KB
    __shared__ alignas(16) _Float16 Bs0[128 * 32];   //  8 KB
    __shared__ alignas(16) _Float16 Bs1[128 * 32];   //  8 KB

    const int t    = threadIdx.x;
    const int lane = t & 63;
    const int wave = t >> 6;
    const int wm   = wave >> 1, wn = wave & 1;

    floatx4 acc[4][4] = {};

    // A: slot G = q*256+t linear in LDS; source granule g = (G&7)^(row&7), row=G>>3.
    uint32_t aoff[4];
    #pragma unroll
    for (int q = 0; q < 4; ++q) {
        const int G   = q * 256 + t;
        const int row = G >> 3;
        const int g   = (G & 7) ^ (row & 7);
        aoff[q] = (uint32_t)((bm * 128 + row) * 2048 + g * 16);
    }
    // B: row-pair swizzle.
    uint32_t boff[2];
    #pragma unroll
    for (int q = 0; q < 2; ++q) {
        const int G     = q * 256 + t;
        const int super = G >> 3;
        const int sgg   = (G & 7) ^ (super & 7);
        const int row   = super * 2 + (sgg >> 2);
        const int g     = sgg & 3;
        boff[q] = (uint32_t)((bn * 128 + row) * 1024 + g * 16);
    }

    const int r0  = lane & 15;
    const int hi  = lane >> 4;
    const int swz = r0 & 7;

    // prologue
    KV_STAGE(As0, Bs0, 0);
    KV_SYNC();

    #pragma unroll 1
    for (int ktp = 0; ktp < 8; ++ktp) {
        const int kt0 = ktp * 2;
        KV_STAGE(As1, Bs1, kt0 + 1);
        KV_COMPUTE(As0, Bs0);
        KV_SYNC();
        if (kt0 + 2 < 16) KV_STAGE(As0, Bs0, kt0 + 2);
        KV_COMPUTE(As1, Bs1);
        if (ktp < 7) KV_SYNC();
    }

    #pragma unroll
    for (int mi = 0; mi < 4; ++mi) {
        #pragma unroll
        for (int ni = 0; ni < 4; ++ni) {
            const int col = bn * 128 + wn * 64 + ni * 16 + (lane & 15);
            const float bv = bias[col];
            #pragma unroll
            for (int r = 0; r < 4; ++r) {
                const int row = bm * 128 + wm * 64 + mi * 16 + (lane >> 4) * 4 + r;
                outp[(size_t)row * CH + col] = (_Float16)(acc[mi][ni][r] + bv);
            }
        }
    }
}

// ---------------- local attention: one block (256 thr) per query ----------------
__global__ __launch_bounds__(256) void attn_kernel(
    const _Float16* __restrict__ q16, const _Float16* __restrict__ k16,
    const _Float16* __restrict__ v16, const int* __restrict__ ipair,
    const int* __restrict__ ibatch, const int* __restrict__ kcnt,
    _Float16* __restrict__ op16, float* __restrict__ aout)
{
    __shared__ uint32_t vmask[LNB];       // row byte-offset | (masked<<31)
    __shared__ float    pls[LNB * 9];     // logits -> probs (stride 9)
    __shared__ __half2  pph[LNB * 9];     // probs pre-packed {p,p} fp16
    __shared__ float    part[4][CH];      // per-wave PV partials

    const int t = threadIdx.x;
    // XCD swizzle: batch b = n/512 -> XCD b (one batch's K+V fp16 fits one L2)
    const int n = ((blockIdx.x & 7) << 9) | (blockIdx.x >> 3);

    if (t < LNB) {
        const int idx = ipair[(size_t)n * LNB + t];
        const int b   = ibatch[n];
        int off = 0;
        for (int i = 0; i < b; ++i) off += kcnt[i];
        const uint32_t vo = (uint32_t)((idx < 0 ? 0 : (idx + off)) * (CH * 2));
        vmask[t] = vo | (idx < 0 ? 0x80000000u : 0u);
    }
    __syncthreads();

    const int lane = t & 63, wv = t >> 6;
    const int h    = lane >> 3;           // head for this lane
    const int l0   = wv * 24;             // wave's contiguous l-chunk

    // ---- phase 1: logits. lane owns dims [lane*8, +8); octet = one head.
    {
        const half8 qv = *(const half8*)(q16 + (size_t)n * CH + lane * 8);
        H8 qu; qu.v = qv;
        const char* kbase = (const char*)k16 + lane * 16;
        const int4* vb = (const int4*)&vmask[l0];
        for (int g = 0; g < 3; ++g) {
            const int4 w0 = vb[2 * g], w1 = vb[2 * g + 1];
            uint32_t vm8[8] = {(uint32_t)w0.x, (uint32_t)w0.y, (uint32_t)w0.z, (uint32_t)w0.w,
                               (uint32_t)w1.x, (uint32_t)w1.y, (uint32_t)w1.z, (uint32_t)w1.w};
            #pragma unroll
            for (int j = 0; j < 8; ++j) {
                const uint32_t vms = __builtin_amdgcn_readfirstlane(vm8[j]);
                H8 ku; ku.v = *(const half8*)(kbase + (vms & 0x7fffffffu));
                float acc = 0.f;
                #pragma unroll
                for (int u = 0; u < 4; ++u)
                    acc = __builtin_amdgcn_fdot2(qu.p[u], ku.p[u], acc, false);
                acc = octet_sum(acc);
                if ((lane & 7) == 0)
                    pls[(l0 + g * 8 + j) * 9 + h] = (vms & 0x80000000u) ? -1e30f : acc;
            }
        }
    }
    __syncthreads();

    // ---- phase 2: softmax over L per head (hh = t>>5, j = t&31)
    {
        const int hh = t >> 5, j = t & 31;
        const float v0 = pls[j * 9 + hh];
        const float v1 = pls[(j + 32) * 9 + hh];
        const float v2 = pls[(j + 64) * 9 + hh];
        float m = fmaxf(v0, fmaxf(v1, v2));
        #pragma unroll
        for (int s = 16; s >= 1; s >>= 1) m = fmaxf(m, __shfl_xor(m, s, 32));
        const float e0 = __expf(v0 - m), e1 = __expf(v1 - m), e2 = __expf(v2 - m);
        float ssum = e0 + e1 + e2;
        #pragma unroll
        for (int s = 16; s >= 1; s >>= 1) ssum += __shfl_xor(ssum, s, 32);
        const float rinv = 1.0f / ssum;
        const float p0 = e0 * rinv, p1 = e1 * rinv, p2 = e2 * rinv;
        pls[j * 9 + hh]        = p0;
        pls[(j + 32) * 9 + hh] = p1;
        pls[(j + 64) * 9 + hh] = p2;
        pph[j * 9 + hh]        = __half2half2(__float2half_rn(p0));
        pph[(j + 32) * 9 + hh] = __half2half2(__float2half_rn(p1));
        pph[(j + 64) * 9 + hh] = __half2half2(__float2half_rn(p2));
    }
    __syncthreads();

    // ---- attn_mean (output 1)
    if (t < LNB) {
        float s = 0.f;
        #pragma unroll
        for (int u = 0; u < NH; ++u) s += pls[t * 9 + u];
        aout[(size_t)n * LNB + t] = s * (1.0f / NH);
    }

    // ---- phase 3: PV. wave owns l in [l0, l0+24), lane owns 8 dims.
    {
        float accf[8] = {};
        const char* vbase = (const char*)v16 + lane * 16;
        const int4* vb = (const int4*)&vmask[l0];
        const __half2 hz = __half2half2(__float2half_rn(0.f));
        for (int g = 0; g < 3; ++g) {
            const int4 w0 = vb[2 * g], w1 = vb[2 * g + 1];
            uint32_t vm8[8] = {(uint32_t)w0.x, (uint32_t)w0.y, (uint32_t)w0.z, (uint32_t)w0.w,
                               (uint32_t)w1.x, (uint32_t)w1.y, (uint32_t)w1.z, (uint32_t)w1.w};
            __half2 a0 = hz, a1 = hz, a2 = hz, a3 = hz;
            #pragma unroll
            for (int j = 0; j < 8; ++j) {
                const uint32_t vms = __builtin_amdgcn_readfirstlane(vm8[j]);
                const half8 vv = *(const half8*)(vbase + (vms & 0x7fffffffu));
                union { half8 v; __half2 q[4]; } vu; vu.v = vv;
                const __half2 pp = pph[(l0 + g * 8 + j) * 9 + h];
                a0 = __hfma2(pp, vu.q[0], a0);
                a1 = __hfma2(pp, vu.q[1], a1);
                a2 = __hfma2(pp, vu.q[2], a2);
                a3 = __hfma2(pp, vu.q[3], a3);
            }
            float2 f;
            f = __half22float2(a0); accf[0] += f.x; accf[1] += f.y;
            f = __half22float2(a1); accf[2] += f.x; accf[3] += f.y;
            f = __half22float2(a2); accf[4] += f.x; accf[5] += f.y;
            f = __half22float2(a3); accf[6] += f.x; accf[7] += f.y;
        }
        floatx4 lo, hi;
        #pragma unroll
        for (int u = 0; u < 4; ++u) { lo[u] = accf[u]; hi[u] = accf[u + 4]; }
        *(floatx4*)&part[wv][lane * 8]     = lo;
        *(floatx4*)&part[wv][lane * 8 + 4] = hi;
    }
    __syncthreads();

    // ---- final cross-wave reduce: thread t owns dims 2t, 2t+1
    {
        const int c = t * 2;
        floatx2 s = *(const floatx2*)&part[0][c];
        #pragma unroll
        for (int w = 1; w < 4; ++w) {
            floatx2 pw = *(const floatx2*)&part[w][c];
            s[0] += pw[0]; s[1] += pw[1];
        }
        h2 o; o[0] = (_Float16)s[0]; o[1] = (_Float16)s[1];
        *(h2*)&op16[(size_t)n * CH + c] = o;
    }
}

extern "C" void kernel_launch(void* const* d_in, const int* in_sizes, int n_in,
                              void* d_out, int out_size, void* d_ws, size_t ws_size,
                              hipStream_t stream)
{
    const float* query = (const float*)d_in[0];
    const float* key   = (const float*)d_in[1];
    const float* value = (const float*)d_in[2];
    const int*   ipair = (const int*)d_in[3];
    const int*   kcnt  = (const int*)d_in[5];
    const int*   ibat  = (const int*)d_in[6];
    const float* wIn   = (const float*)d_in[7];
    const float* bIn   = (const float*)d_in[8];
    const float* wOut  = (const float*)d_in[9];
    const float* bOut  = (const float*)d_in[10];

    float* out  = (float*)d_out;
    float* aout = out + (size_t)N_Q * CH;

    char* ws = (char*)d_ws;
    _Float16* w16  = (_Float16*)(ws);                // in-proj weights fp16 (1.5MB)
    _Float16* wo16 = (_Float16*)(ws + 1572864);      // out-proj weights fp16 (contiguous)
    _Float16* q16  = (_Float16*)(ws + 2097152);      // 4MB
    _Float16* k16  = (_Float16*)(ws + 6291456);      // 16MB
    _Float16* v16  = (_Float16*)(ws + 23068672);     // 16MB
    _Float16* op16 = (_Float16*)(ws + 39845888);     // 4MB

    // one fused weight convert (wIn ++ wOut -> w16 ++ wo16)
    cvt_weights<<<1024, 256, 0, stream>>>(wIn, wOut, w16);

    // Q projection with fused fp32->fp16 A staging (scaling folded in)
    gemm_k<1, 64, 1><<<256, 256, 0, stream>>>(query, w16, bIn, q16, 0.125f);

    // K/V projections: double-buffered pipeline, fp32 A direct-to-LDS, XCD-grouped
    gemm_kv<<<1024, 256, 0, stream>>>(key, value, w16, bIn, k16, v16);

    attn_kernel<<<4096, 256, 0, stream>>>(q16, k16, v16, ipair, ibat, kcnt, op16, aout);

    gemm_k<0, 64, 0><<<256, 256, 0, stream>>>(op16, wo16, bOut, d_out, 1.0f);
}

// Round 9
// 98.222 us; speedup vs baseline: 1.4600x; 1.0175x over previous
//
#include <hip/hip_runtime.h>
#include <hip/hip_fp16.h>
#include <cstdint>
#include <cstddef>

#define N_Q 4096
#define M_K 16384
#define LNB 96
#define CH  512
#define NH  8

typedef _Float16 half8  __attribute__((ext_vector_type(8)));
typedef _Float16 h2     __attribute__((ext_vector_type(2)));
typedef float    floatx4 __attribute__((ext_vector_type(4)));
typedef float    floatx2 __attribute__((ext_vector_type(2)));

union H8 { half8 v; h2 p[4]; };

__device__ __forceinline__ h2 cvt2(float a, float b) {
    return __builtin_bit_cast(h2, __builtin_amdgcn_cvt_pkrtz(a, b));
}

__device__ __forceinline__ void async16(const void* g, void* l) {
    __builtin_amdgcn_global_load_lds(
        (const __attribute__((address_space(1))) void*)g,
        (__attribute__((address_space(3))) void*)l, 16, 0, 0);
}

// DPP butterfly add over an 8-lane octet (pure VALU).
template<int CTRL>
__device__ __forceinline__ float dpp_addf(float x) {
    int xi = __builtin_bit_cast(int, x);
    int yi = __builtin_amdgcn_update_dpp(xi, xi, CTRL, 0xF, 0xF, false);
    return x + __builtin_bit_cast(float, yi);
}
__device__ __forceinline__ float octet_sum(float x) {
    x = dpp_addf<0x141>(x);   // row_half_mirror
    x = dpp_addf<0x4E>(x);    // quad xor2
    x = dpp_addf<0xB1>(x);    // quad xor1
    return x;
}

// ---------------- fused weight convert: wIn (786432 f) ++ wOut (262144 f) -> fp16
__global__ void cvt_weights(const float* __restrict__ wIn, const float* __restrict__ wOut,
                            _Float16* __restrict__ dst) {
    const size_t i = (size_t)blockIdx.x * blockDim.x + threadIdx.x;   // float4 index
    const float4 v = (i < 196608) ? ((const float4*)wIn)[i]
                                  : ((const float4*)wOut)[i - 196608];
    h2 a = cvt2(v.x, v.y);
    h2 b = cvt2(v.z, v.w);
    *(h2*)&dst[i * 4]     = a;
    *(h2*)&dst[i * 4 + 2] = b;
}

// ---------------- small GEMM body (TM x 128, BK=32), used for Q and out proj ----
template<int OUTF16, int TM, int AFP32>
__device__ __forceinline__ void gemm_body(
    const void* __restrict__ Ap, const _Float16* __restrict__ Bw,
    const float* __restrict__ bias, void* __restrict__ outp, float oscale,
    int bm, int bn)
{
    constexpr int MI = TM / 32;
    __shared__ alignas(16) _Float16 As[TM * 32];
    __shared__ alignas(16) _Float16 Bs[128 * 32];

    const int t    = threadIdx.x;
    const int lane = t & 63;
    const int wave = t >> 6;
    const int wm   = wave >> 1, wn = wave & 1;

    floatx4 acc[MI][4] = {};

    const int rowL = t >> 2;
    const int kcol = (t & 3) * 8;
    const _Float16* gB = Bw + (size_t)(bn * 128 + rowL) * CH + kcol;
    _Float16* lB = &Bs[rowL * 32 + kcol];

    const _Float16* gA16 = nullptr; _Float16* lA16 = nullptr;
    const float* gA32 = nullptr; _Float16* lA32 = nullptr;
    if constexpr (AFP32) {
        gA32 = (const float*)Ap + (size_t)(bm * TM + rowL) * CH + kcol;
        lA32 = &As[rowL * 32 + kcol];
    } else {
        gA16 = (const _Float16*)Ap + (size_t)(bm * TM + rowL) * CH + kcol;
        lA16 = &As[rowL * 32 + kcol];
    }

    const int r0 = lane & 15;
    const int ko = (lane >> 4) * 8;

    for (int kt = 0; kt < CH / 32; ++kt) {
        if constexpr (AFP32) {
            const float* ga = gA32 + kt * 32;
            float4 x0 = ((const float4*)ga)[0], x1 = ((const float4*)ga)[1];
            H8 o0;
            o0.p[0] = cvt2(x0.x, x0.y);
            o0.p[1] = cvt2(x0.z, x0.w);
            o0.p[2] = cvt2(x1.x, x1.y);
            o0.p[3] = cvt2(x1.z, x1.w);
            *(half8*)lA32 = o0.v;
        } else {
            const _Float16* a0 = gA16 + kt * 32;
            async16(a0, lA16);
        }
        const _Float16* b0 = gB + kt * 32;
        async16(b0,           lB);
        async16(b0 + 64 * CH, lB + 64 * 32);
        __syncthreads();

        half8 af[MI], bf[4];
        #pragma unroll
        for (int mi = 0; mi < MI; ++mi)
            af[mi] = *(const half8*)&As[(wm * (TM / 2) + mi * 16 + r0) * 32 + ko];
        #pragma unroll
        for (int ni = 0; ni < 4; ++ni)
            bf[ni] = *(const half8*)&Bs[(wn * 64 + ni * 16 + r0) * 32 + ko];
        #pragma unroll
        for (int mi = 0; mi < MI; ++mi)
            #pragma unroll
            for (int ni = 0; ni < 4; ++ni)
                acc[mi][ni] = __builtin_amdgcn_mfma_f32_16x16x32_f16(
                    af[mi], bf[ni], acc[mi][ni], 0, 0, 0);
        __syncthreads();
    }

    #pragma unroll
    for (int mi = 0; mi < MI; ++mi) {
        #pragma unroll
        for (int ni = 0; ni < 4; ++ni) {
            const int col = bn * 128 + wn * 64 + ni * 16 + (lane & 15);
            const float bv = bias[col];
            #pragma unroll
            for (int r = 0; r < 4; ++r) {
                const int row = bm * TM + wm * (TM / 2) + mi * 16 + (lane >> 4) * 4 + r;
                const float v = (acc[mi][ni][r] + bv) * oscale;
                if (OUTF16) ((_Float16*)outp)[(size_t)row * CH + col] = (_Float16)v;
                else        ((float*)outp)[(size_t)row * CH + col]    = v;
            }
        }
    }
}

// XCD-grouped decode: blocks sharing an A-tile (same bm, 4 bn's) land on ONE XCD.
template<int OUTF16, int TM, int AFP32>
__global__ __launch_bounds__(256) void gemm_k(
    const void* __restrict__ A, const _Float16* __restrict__ Bw,
    const float* __restrict__ bias, void* __restrict__ outp, float oscale)
{
    const int bid = blockIdx.x;
    const int x   = bid & 7;
    const int i   = bid >> 3;
    const int bn  = i & 3;
    const int bm  = x + 8 * (i >> 2);
    gemm_body<OUTF16, TM, AFP32>(A, Bw, bias, outp, oscale, bm, bn);
}

// ---------------- K/V projection GEMM: T3+T4 (depth-2 prefetch, COUNTED vmcnt) --
// fp32 A direct-to-LDS (global_load_lds), cvt after ds_read, swizzled (rule #21).
// 6 loads/thread/stage; wait vmcnt(6) = only the OLDER stage must land, the
// newer 6 loads stay in flight across the barrier (T4 — never drain to 0 in loop).
#define KV_STAGE(AS, BS, KT) do {                                               \
    _Pragma("unroll")                                                           \
    for (int q = 0; q < 4; ++q)                                                 \
        async16(Ab + aoff[q] + (KT) * 128, (char*)(AS) + (q * 256 + t) * 16);   \
    _Pragma("unroll")                                                           \
    for (int q = 0; q < 2; ++q)                                                 \
        async16(Bb + boff[q] + (KT) * 64,  (char*)(BS) + (q * 256 + t) * 16);   \
    __builtin_amdgcn_sched_barrier(0);                                          \
} while (0)

#define KV_COMPUTE(AS, BS) do {                                                 \
    half8 af[4], bf[4];                                                         \
    _Pragma("unroll")                                                           \
    for (int mi = 0; mi < 4; ++mi) {                                            \
        const int row = wm * 64 + mi * 16 + r0;                                 \
        const float4 x0 = *(const float4*)((const char*)(AS) + row * 128 + (((hi * 2)     ^ swz) * 16)); \
        const float4 x1 = *(const float4*)((const char*)(AS) + row * 128 + (((hi * 2 + 1) ^ swz) * 16)); \
        H8 o;                                                                   \
        o.p[0] = cvt2(x0.x, x0.y);                                              \
        o.p[1] = cvt2(x0.z, x0.w);                                              \
        o.p[2] = cvt2(x1.x, x1.y);                                              \
        o.p[3] = cvt2(x1.z, x1.w);                                              \
        af[mi] = o.v;                                                           \
    }                                                                           \
    _Pragma("unroll")                                                           \
    for (int ni = 0; ni < 4; ++ni) {                                            \
        const int row   = wn * 64 + ni * 16 + r0;                               \
        const int super = row >> 1;                                             \
        const int vv    = ((row & 1) * 4 + hi) ^ (super & 7);                   \
        bf[ni] = *(const half8*)((const char*)(BS) + super * 128 + vv * 16);    \
    }                                                                           \
    _Pragma("unroll")                                                           \
    for (int mi = 0; mi < 4; ++mi)                                              \
        _Pragma("unroll")                                                       \
        for (int ni = 0; ni < 4; ++ni)                                          \
            acc[mi][ni] = __builtin_amdgcn_mfma_f32_16x16x32_f16(               \
                af[mi], bf[ni], acc[mi][ni], 0, 0, 0);                          \
} while (0)

#define VWAIT(N) do {                                                           \
    asm volatile("s_waitcnt vmcnt(" #N ")" ::: "memory");                       \
    __builtin_amdgcn_sched_barrier(0);                                          \
} while (0)
#define LWAIT() do {                                                            \
    asm volatile("s_waitcnt lgkmcnt(0)" ::: "memory");                          \
    __builtin_amdgcn_sched_barrier(0);                                          \
} while (0)
#define BAR() do {                                                              \
    __builtin_amdgcn_s_barrier();                                               \
    __builtin_amdgcn_sched_barrier(0);                                          \
} while (0)

__global__ __launch_bounds__(256) void gemm_kv(
    const float* __restrict__ keyp, const float* __restrict__ valp,
    const _Float16* __restrict__ w16, const float* __restrict__ bIn,
    _Float16* __restrict__ k16, _Float16* __restrict__ v16)
{
    const int bid = blockIdx.x;
    const int x   = bid & 7;          // XCD
    const int i   = bid >> 3;         // 0..127
    const int bn  = i & 3;
    const int z   = (i >> 2) & 1;
    const int bm  = x + 8 * (i >> 3); // 0..127

    const char*     Ab   = (const char*)(z ? valp : keyp);
    const char*     Bb   = (const char*)(w16 + (size_t)(z ? 1024 : 512) * 512);
    const float*    bias = bIn + (z ? 1024 : 512);
    _Float16*       outp = z ? v16 : k16;

    __shared__ alignas(16) float    As0[128 * 32];   // 16 KB
    __shared__ alignas(16) float    As1[128 * 32];   // 16 KB
    __shared__ alignas(16) _Float16 Bs0[128 * 32];   //  8 KB
    __shared__ alignas(16) _Float16 Bs1[128 * 32];   //  8 KB

    const int t    = threadIdx.x;
    const int lane = t & 63;
    const int wave = t >> 6;
    const int wm   = wave >> 1, wn = wave & 1;

    floatx4 acc[4][4] = {};

    // A: slot G = q*256+t linear in LDS; source granule g = (G&7)^(row&7), row=G>>3.
    uint32_t aoff[4];
    #pragma unroll
    for (int q = 0; q < 4; ++q) {
        const int G   = q * 256 + t;
        const int row = G >> 3;
        const int g   = (G & 7) ^ (row & 7);
        aoff[q] = (uint32_t)((bm * 128 + row) * 2048 + g * 16);
    }
    // B: row-pair swizzle.
    uint32_t boff[2];
    #pragma unroll
    for (int q = 0; q < 2; ++q) {
        const int G     = q * 256 + t;
        const int super = G >> 3;
        const int sgg   = (G & 7) ^ (super & 7);
        const int row   = super * 2 + (sgg >> 2);
        const int g     = sgg & 3;
        boff[q] = (uint32_t)((bn * 128 + row) * 1024 + g * 16);
    }

    const int r0  = lane & 15;
    const int hi  = lane >> 4;
    const int swz = r0 & 7;

    // prologue: 2 stages in flight (12 loads/thread)
    KV_STAGE(As0, Bs0, 0);
    KV_STAGE(As1, Bs1, 1);

    #pragma unroll 1
    for (int ktp = 0; ktp < 7; ++ktp) {
        VWAIT(6); BAR();                 // older stage landed; newer 6 in flight
        KV_COMPUTE(As0, Bs0);
        LWAIT(); BAR();                  // all waves done reading buf0
        KV_STAGE(As0, Bs0, 2 * ktp + 2);
        VWAIT(6); BAR();
        KV_COMPUTE(As1, Bs1);
        LWAIT(); BAR();
        KV_STAGE(As1, Bs1, 2 * ktp + 3);
    }
    // kt=14: 12 in flight -> wait oldest 6
    VWAIT(6); BAR();
    KV_COMPUTE(As0, Bs0);
    // kt=15: last 6 in flight
    VWAIT(0); BAR();
    KV_COMPUTE(As1, Bs1);

    #pragma unroll
    for (int mi = 0; mi < 4; ++mi) {
        #pragma unroll
        for (int ni = 0; ni < 4; ++ni) {
            const int col = bn * 128 + wn * 64 + ni * 16 + (lane & 15);
            const float bv = bias[col];
            #pragma unroll
            for (int r = 0; r < 4; ++r) {
                const int row = bm * 128 + wm * 64 + mi * 16 + (lane >> 4) * 4 + r;
                outp[(size_t)row * CH + col] = (_Float16)(acc[mi][ni][r] + bv);
            }
        }
    }
}

// ---------------- local attention: one block (256 thr) per query ----------------
__global__ __launch_bounds__(256) void attn_kernel(
    const _Float16* __restrict__ q16, const _Float16* __restrict__ k16,
    const _Float16* __restrict__ v16, const int* __restrict__ ipair,
    const int* __restrict__ ibatch, const int* __restrict__ kcnt,
    _Float16* __restrict__ op16, float* __restrict__ aout)
{
    __shared__ uint32_t vmask[LNB];       // row byte-offset | (masked<<31)
    __shared__ float    pls[LNB * 9];     // logits -> probs (stride 9)
    __shared__ __half2  pph[LNB * 9];     // probs pre-packed {p,p} fp16
    __shared__ float    part[4][CH];      // per-wave PV partials

    const int t = threadIdx.x;
    // XCD swizzle: batch b = n/512 -> XCD b (one batch's K+V fp16 fits one L2)
    const int n = ((blockIdx.x & 7) << 9) | (blockIdx.x >> 3);

    if (t < LNB) {
        const int idx = ipair[(size_t)n * LNB + t];
        const int b   = ibatch[n];
        int off = 0;
        for (int i = 0; i < b; ++i) off += kcnt[i];
        const uint32_t vo = (uint32_t)((idx < 0 ? 0 : (idx + off)) * (CH * 2));
        vmask[t] = vo | (idx < 0 ? 0x80000000u : 0u);
    }
    __syncthreads();

    const int lane = t & 63, wv = t >> 6;
    const int h    = lane >> 3;           // head for this lane
    const int l0   = wv * 24;             // wave's contiguous l-chunk

    // ---- phase 1: logits. lane owns dims [lane*8, +8); octet = one head.
    {
        const half8 qv = *(const half8*)(q16 + (size_t)n * CH + lane * 8);
        H8 qu; qu.v = qv;
        const char* kbase = (const char*)k16 + lane * 16;
        const int4* vb = (const int4*)&vmask[l0];
        for (int g = 0; g < 3; ++g) {
            const int4 w0 = vb[2 * g], w1 = vb[2 * g + 1];
            uint32_t vm8[8] = {(uint32_t)w0.x, (uint32_t)w0.y, (uint32_t)w0.z, (uint32_t)w0.w,
                               (uint32_t)w1.x, (uint32_t)w1.y, (uint32_t)w1.z, (uint32_t)w1.w};
            #pragma unroll
            for (int j = 0; j < 8; ++j) {
                const uint32_t vms = __builtin_amdgcn_readfirstlane(vm8[j]);
                H8 ku; ku.v = *(const half8*)(kbase + (vms & 0x7fffffffu));
                float acc = 0.f;
                #pragma unroll
                for (int u = 0; u < 4; ++u)
                    acc = __builtin_amdgcn_fdot2(qu.p[u], ku.p[u], acc, false);
                acc = octet_sum(acc);
                if ((lane & 7) == 0)
                    pls[(l0 + g * 8 + j) * 9 + h] = (vms & 0x80000000u) ? -1e30f : acc;
            }
        }
    }
    __syncthreads();

    // ---- phase 2: softmax over L per head (hh = t>>5, j = t&31)
    {
        const int hh = t >> 5, j = t & 31;
        const float v0 = pls[j * 9 + hh];
        const float v1 = pls[(j + 32) * 9 + hh];
        const float v2 = pls[(j + 64) * 9 + hh];
        float m = fmaxf(v0, fmaxf(v1, v2));
        #pragma unroll
        for (int s = 16; s >= 1; s >>= 1) m = fmaxf(m, __shfl_xor(m, s, 32));
        const float e0 = __expf(v0 - m), e1 = __expf(v1 - m), e2 = __expf(v2 - m);
        float ssum = e0 + e1 + e2;
        #pragma unroll
        for (int s = 16; s >= 1; s >>= 1) ssum += __shfl_xor(ssum, s, 32);
        const float rinv = 1.0f / ssum;
        const float p0 = e0 * rinv, p1 = e1 * rinv, p2 = e2 * rinv;
        pls[j * 9 + hh]        = p0;
        pls[(j + 32) * 9 + hh] = p1;
        pls[(j + 64) * 9 + hh] = p2;
        pph[j * 9 + hh]        = __half2half2(__float2half_rn(p0));
        pph[(j + 32) * 9 + hh] = __half2half2(__float2half_rn(p1));
        pph[(j + 64) * 9 + hh] = __half2half2(__float2half_rn(p2));
    }
    __syncthreads();

    // ---- attn_mean (output 1)
    if (t < LNB) {
        float s = 0.f;
        #pragma unroll
        for (int u = 0; u < NH; ++u) s += pls[t * 9 + u];
        aout[(size_t)n * LNB + t] = s * (1.0f / NH);
    }

    // ---- phase 3: PV. wave owns l in [l0, l0+24), lane owns 8 dims.
    {
        float accf[8] = {};
        const char* vbase = (const char*)v16 + lane * 16;
        const int4* vb = (const int4*)&vmask[l0];
        const __half2 hz = __half2half2(__float2half_rn(0.f));
        for (int g = 0; g < 3; ++g) {
            const int4 w0 = vb[2 * g], w1 = vb[2 * g + 1];
            uint32_t vm8[8] = {(uint32_t)w0.x, (uint32_t)w0.y, (uint32_t)w0.z, (uint32_t)w0.w,
                               (uint32_t)w1.x, (uint32_t)w1.y, (uint32_t)w1.z, (uint32_t)w1.w};
            __half2 a0 = hz, a1 = hz, a2 = hz, a3 = hz;
            #pragma unroll
            for (int j = 0; j < 8; ++j) {
                const uint32_t vms = __builtin_amdgcn_readfirstlane(vm8[j]);
                const half8 vv = *(const half8*)(vbase + (vms & 0x7fffffffu));
                union { half8 v; __half2 q[4]; } vu; vu.v = vv;
                const __half2 pp = pph[(l0 + g * 8 + j) * 9 + h];
                a0 = __hfma2(pp, vu.q[0], a0);
                a1 = __hfma2(pp, vu.q[1], a1);
                a2 = __hfma2(pp, vu.q[2], a2);
                a3 = __hfma2(pp, vu.q[3], a3);
            }
            float2 f;
            f = __half22float2(a0); accf[0] += f.x; accf[1] += f.y;
            f = __half22float2(a1); accf[2] += f.x; accf[3] += f.y;
            f = __half22float2(a2); accf[4] += f.x; accf[5] += f.y;
            f = __half22float2(a3); accf[6] += f.x; accf[7] += f.y;
        }
        floatx4 lo, hi;
        #pragma unroll
        for (int u = 0; u < 4; ++u) { lo[u] = accf[u]; hi[u] = accf[u + 4]; }
        *(floatx4*)&part[wv][lane * 8]     = lo;
        *(floatx4*)&part[wv][lane * 8 + 4] = hi;
    }
    __syncthreads();

    // ---- final cross-wave reduce: thread t owns dims 2t, 2t+1
    {
        const int c = t * 2;
        floatx2 s = *(const floatx2*)&part[0][c];
        #pragma unroll
        for (int w = 1; w < 4; ++w) {
            floatx2 pw = *(const floatx2*)&part[w][c];
            s[0] += pw[0]; s[1] += pw[1];
        }
        h2 o; o[0] = (_Float16)s[0]; o[1] = (_Float16)s[1];
        *(h2*)&op16[(size_t)n * CH + c] = o;
    }
}

extern "C" void kernel_launch(void* const* d_in, const int* in_sizes, int n_in,
                              void* d_out, int out_size, void* d_ws, size_t ws_size,
                              hipStream_t stream)
{
    const float* query = (const float*)d_in[0];
    const float* key   = (const float*)d_in[1];
    const float* value = (const float*)d_in[2];
    const int*   ipair = (const int*)d_in[3];
    const int*   kcnt  = (const int*)d_in[5];
    const int*   ibat  = (const int*)d_in[6];
    const float* wIn   = (const float*)d_in[7];
    const float* bIn   = (const float*)d_in[8];
    const float* wOut  = (const float*)d_in[9];
    const float* bOut  = (const float*)d_in[10];

    float* out  = (float*)d_out;
    float* aout = out + (size_t)N_Q * CH;

    char* ws = (char*)d_ws;
    _Float16* w16  = (_Float16*)(ws);                // in-proj weights fp16 (1.5MB)
    _Float16* wo16 = (_Float16*)(ws + 1572864);      // out-proj weights fp16 (contiguous)
    _Float16* q16  = (_Float16*)(ws + 2097152);      // 4MB
    _Float16* k16  = (_Float16*)(ws + 6291456);      // 16MB
    _Float16* v16  = (_Float16*)(ws + 23068672);     // 16MB
    _Float16* op16 = (_Float16*)(ws + 39845888);     // 4MB

    // one fused weight convert (wIn ++ wOut -> w16 ++ wo16)
    cvt_weights<<<1024, 256, 0, stream>>>(wIn, wOut, w16);

    // Q projection with fused fp32->fp16 A staging (scaling folded in)
    gemm_k<1, 64, 1><<<256, 256, 0, stream>>>(query, w16, bIn, q16, 0.125f);

    // K/V projections: depth-2 prefetch with COUNTED vmcnt (T4), XCD-grouped
    gemm_kv<<<1024, 256, 0, stream>>>(key, value, w16, bIn, k16, v16);

    attn_kernel<<<4096, 256, 0, stream>>>(q16, k16, v16, ipair, ibat, kcnt, op16, aout);

    gemm_k<0, 64, 0><<<256, 256, 0, stream>>>(op16, wo16, bOut, d_out, 1.0f);
}